// Round 1
// baseline (3432.872 us; speedup 1.0000x reference)
//
#include <hip/hip_runtime.h>
#include <math.h>

#define SS 1024
#define BB 4
#define DD 1024
#define HH 16
#define FFF 4096
#define MM (SS*BB)   // 4096 token rows

// ---------------- RMSNorm: one block (256 thr) per row ----------------
__global__ void rmsnorm_kernel(const float* __restrict__ x, const float* __restrict__ g,
                               float* __restrict__ out) {
    int row = blockIdx.x;
    const float* xr = x + (size_t)row * DD;
    float* orow = out + (size_t)row * DD;
    int tid = threadIdx.x;
    float4 v = *reinterpret_cast<const float4*>(xr + tid * 4);
    float ss = v.x*v.x + v.y*v.y + v.z*v.z + v.w*v.w;
    #pragma unroll
    for (int off = 32; off; off >>= 1) ss += __shfl_down(ss, off);
    __shared__ float part[4];
    if ((tid & 63) == 0) part[tid >> 6] = ss;
    __syncthreads();
    float tot = part[0] + part[1] + part[2] + part[3];
    float rms = sqrtf(tot) * (1.0f / 32.0f);      // ||x|| / sqrt(1024)
    float inv = 1.0f / (rms + 1e-8f);
    float4 gv = *reinterpret_cast<const float4*>(g + tid * 4);
    float4 o;
    o.x = gv.x * v.x * inv;
    o.y = gv.y * v.y * inv;
    o.z = gv.z * v.z * inv;
    o.w = gv.w * v.w * inv;
    *reinterpret_cast<float4*>(orow + tid * 4) = o;
}

// ---------------- fp32 tiled GEMM: C[M,N] = A[M,K] @ W[K,N] + bias ----------------
// BM=128, BN=64, BK=16; 256 threads; per-thread 8x4 microtile.
// EPI: 0 = bias only, 1 = bias + silu, 2 = bias + residual
template<int EPI>
__global__ void gemm_kernel(const float* __restrict__ A, const float* __restrict__ W,
                            const float* __restrict__ bias, const float* __restrict__ res,
                            float* __restrict__ C, int K, int N) {
    __shared__ float As[16][132];   // transposed: As[k][m], pad 132
    __shared__ float Bs[16][68];    // Bs[k][n], pad 68
    int tid = threadIdx.x;
    int tx = tid & 15, ty = tid >> 4;
    int brow = blockIdx.y * 128;
    int bcol = blockIdx.x * 64;
    float acc[8][4] = {};
    for (int kt = 0; kt < K; kt += 16) {
        #pragma unroll
        for (int i = 0; i < 2; i++) {
            int flat = tid + i * 256;            // 0..511
            int r = flat >> 2;                   // 0..127
            int kg = (flat & 3) * 4;             // 0,4,8,12
            float4 a = *reinterpret_cast<const float4*>(A + (size_t)(brow + r) * K + kt + kg);
            As[kg + 0][r] = a.x; As[kg + 1][r] = a.y;
            As[kg + 2][r] = a.z; As[kg + 3][r] = a.w;
        }
        {
            int r = tid >> 4;
            int c = (tid & 15) * 4;
            *reinterpret_cast<float4*>(&Bs[r][c]) =
                *reinterpret_cast<const float4*>(W + (size_t)(kt + r) * N + bcol + c);
        }
        __syncthreads();
        #pragma unroll
        for (int kk = 0; kk < 16; kk++) {
            float4 a0 = *reinterpret_cast<const float4*>(&As[kk][ty * 8]);
            float4 a1 = *reinterpret_cast<const float4*>(&As[kk][ty * 8 + 4]);
            float4 b0 = *reinterpret_cast<const float4*>(&Bs[kk][tx * 4]);
            float av[8] = {a0.x, a0.y, a0.z, a0.w, a1.x, a1.y, a1.z, a1.w};
            float bv[4] = {b0.x, b0.y, b0.z, b0.w};
            #pragma unroll
            for (int i = 0; i < 8; i++)
                #pragma unroll
                for (int j = 0; j < 4; j++)
                    acc[i][j] += av[i] * bv[j];
        }
        __syncthreads();
    }
    float4 bv = *reinterpret_cast<const float4*>(bias + bcol + tx * 4);
    #pragma unroll
    for (int i = 0; i < 8; i++) {
        int row = brow + ty * 8 + i;
        float4 o;
        o.x = acc[i][0] + bv.x;
        o.y = acc[i][1] + bv.y;
        o.z = acc[i][2] + bv.z;
        o.w = acc[i][3] + bv.w;
        if (EPI == 1) {
            o.x = o.x / (1.0f + __expf(-o.x));
            o.y = o.y / (1.0f + __expf(-o.y));
            o.z = o.z / (1.0f + __expf(-o.z));
            o.w = o.w / (1.0f + __expf(-o.w));
        }
        if (EPI == 2) {
            float4 rv = *reinterpret_cast<const float4*>(res + (size_t)row * N + bcol + tx * 4);
            o.x += rv.x; o.y += rv.y; o.z += rv.z; o.w += rv.w;
        }
        *reinterpret_cast<float4*>(C + (size_t)row * N + bcol + tx * 4) = o;
    }
}

// ---------------- RoPE on first 32 dims of each 64-dim head ----------------
__global__ void rope_kernel(float* __restrict__ X) {
    int idx = blockIdx.x * 256 + threadIdx.x;   // M*H*16 total
    int pair = idx & 15;
    int hh = (idx >> 4) & 15;
    int row = idx >> 8;          // 0..M-1,  row = s*B + b
    int s = row >> 2;            // B = 4
    float inv = powf(10000.0f, -(float)pair / 16.0f);
    float ang = (float)s * inv;
    float c = cosf(ang), sn = sinf(ang);
    float* p = X + (size_t)row * DD + hh * 64 + pair * 2;
    float x0 = p[0], x1 = p[1];
    p[0] = x0 * c - x1 * sn;
    p[1] = x1 * c + x0 * sn;
}

// ---------------- Flash attention (fp32 SIMT) ----------------
// grid: (S/16, B*H); block 256 = 4 waves; wave w handles q rows qb+w*4 .. +3
template<bool CAUSAL>
__global__ void attn_kernel(const float* __restrict__ Q, const float* __restrict__ K,
                            const float* __restrict__ V, const int* __restrict__ mask,
                            float* __restrict__ O) {
    __shared__ float Kt[64][65];
    __shared__ float Vt[64][65];
    __shared__ float Qs[16][65];
    __shared__ float Ps[4][4][68];
    int tid = threadIdx.x;
    int lane = tid & 63, w = tid >> 6;
    int bh = blockIdx.y;
    int b = bh >> 4, hh = bh & 15;
    int qb = blockIdx.x * 16;
    for (int idx = tid; idx < 16 * 64; idx += 256) {
        int r = idx >> 6, d = idx & 63;
        Qs[r][d] = Q[(size_t)((qb + r) * BB + b) * DD + hh * 64 + d] * 0.125f;
    }
    float m[4], l[4], o[4];
    #pragma unroll
    for (int r = 0; r < 4; r++) { m[r] = -1e38f; l[r] = 0.f; o[r] = 0.f; }
    int q0 = qb + w * 4;
    int ntiles = CAUSAL ? (qb >> 6) + 1 : (SS >> 6);
    for (int t = 0; t < ntiles; t++) {
        __syncthreads();
        for (int idx = tid; idx < 64 * 64; idx += 256) {
            int r = idx >> 6, d = idx & 63;
            Kt[r][d] = K[(size_t)((t * 64 + r) * BB + b) * DD + hh * 64 + d];
            Vt[r][d] = V[(size_t)((t * 64 + r) * BB + b) * DD + hh * 64 + d];
        }
        __syncthreads();
        float sc[4] = {0.f, 0.f, 0.f, 0.f};
        for (int d = 0; d < 64; d++) {
            float kv = Kt[lane][d];
            #pragma unroll
            for (int r = 0; r < 4; r++) sc[r] += Qs[w * 4 + r][d] * kv;
        }
        int key = t * 64 + lane;
        if (CAUSAL) {
            #pragma unroll
            for (int r = 0; r < 4; r++)
                if (mask[(size_t)(q0 + r) * SS + key] == 0) sc[r] = -1e9f;
        }
        #pragma unroll
        for (int r = 0; r < 4; r++) {
            float mx = sc[r];
            #pragma unroll
            for (int off = 32; off; off >>= 1) mx = fmaxf(mx, __shfl_xor(mx, off));
            float nm = fmaxf(m[r], mx);
            float alpha = __expf(m[r] - nm);
            float p = __expf(sc[r] - nm);
            float ps = p;
            #pragma unroll
            for (int off = 32; off; off >>= 1) ps += __shfl_xor(ps, off);
            l[r] = l[r] * alpha + ps;
            o[r] *= alpha;
            m[r] = nm;
            Ps[w][r][lane] = p;
        }
        for (int j = 0; j < 64; j++) {
            float vv = Vt[j][lane];
            #pragma unroll
            for (int r = 0; r < 4; r++) o[r] += Ps[w][r][j] * vv;
        }
    }
    #pragma unroll
    for (int r = 0; r < 4; r++)
        O[(size_t)((q0 + r) * BB + b) * DD + hh * 64 + lane] = o[r] / l[r];
}

extern "C" void kernel_launch(void* const* d_in, const int* in_sizes, int n_in,
                              void* d_out, int out_size, void* d_ws, size_t ws_size,
                              hipStream_t stream) {
    const float* x    = (const float*)d_in[0];
    const float* enc  = (const float*)d_in[1];
    const int*   mask = (const int*)d_in[2];
    const float* sa_wq = (const float*)d_in[3];
    const float* sa_bq = (const float*)d_in[4];
    const float* sa_wk = (const float*)d_in[5];
    const float* sa_bk = (const float*)d_in[6];
    const float* sa_wv = (const float*)d_in[7];
    const float* sa_bv = (const float*)d_in[8];
    const float* sa_wo = (const float*)d_in[9];
    const float* sa_bo = (const float*)d_in[10];
    const float* ca_wq = (const float*)d_in[11];
    const float* ca_bq = (const float*)d_in[12];
    const float* ca_wk = (const float*)d_in[13];
    const float* ca_bk = (const float*)d_in[14];
    const float* ca_wv = (const float*)d_in[15];
    const float* ca_bv = (const float*)d_in[16];
    const float* ca_wo = (const float*)d_in[17];
    const float* ca_bo = (const float*)d_in[18];
    const float* ff_w1 = (const float*)d_in[19];
    const float* ff_b1 = (const float*)d_in[20];
    const float* ff_w2 = (const float*)d_in[21];
    const float* ff_b2 = (const float*)d_in[22];
    const float* g1 = (const float*)d_in[23];
    const float* g2 = (const float*)d_in[24];
    const float* g3 = (const float*)d_in[25];
    float* out = (float*)d_out;
    float* ws = (float*)d_ws;

    const size_t MD = (size_t)MM * DD;
    float* xn   = ws;
    float* q    = ws + 1 * MD;
    float* k    = ws + 2 * MD;
    float* v    = ws + 3 * MD;
    float* attn = ws + 4 * MD;
    float* x1   = ws + 5 * MD;
    float* x2   = ws + 6 * MD;
    float* h    = ws + 1 * MD;   // reuse q..attn region: M*FF = 4*MD floats

    dim3 blk(256);
    dim3 gD(DD / 64, MM / 128);    // N=1024 GEMMs
    dim3 gF1(FFF / 64, MM / 128);  // N=4096
    dim3 gAtt(SS / 16, BB * HH);

    // --- self-attention block ---
    rmsnorm_kernel<<<MM, blk, 0, stream>>>(x, g1, xn);
    gemm_kernel<0><<<gD, blk, 0, stream>>>(xn, sa_wq, sa_bq, nullptr, q, DD, DD);
    gemm_kernel<0><<<gD, blk, 0, stream>>>(xn, sa_wk, sa_bk, nullptr, k, DD, DD);
    gemm_kernel<0><<<gD, blk, 0, stream>>>(xn, sa_wv, sa_bv, nullptr, v, DD, DD);
    rope_kernel<<<(MM * HH * 16) / 256, blk, 0, stream>>>(q);
    rope_kernel<<<(MM * HH * 16) / 256, blk, 0, stream>>>(k);
    attn_kernel<true><<<gAtt, blk, 0, stream>>>(q, k, v, mask, attn);
    gemm_kernel<2><<<gD, blk, 0, stream>>>(attn, sa_wo, sa_bo, x, x1, DD, DD);

    // --- cross-attention block ---
    rmsnorm_kernel<<<MM, blk, 0, stream>>>(x1, g2, xn);
    gemm_kernel<0><<<gD, blk, 0, stream>>>(xn, ca_wq, ca_bq, nullptr, q, DD, DD);
    gemm_kernel<0><<<gD, blk, 0, stream>>>(enc, ca_wk, ca_bk, nullptr, k, DD, DD);
    gemm_kernel<0><<<gD, blk, 0, stream>>>(enc, ca_wv, ca_bv, nullptr, v, DD, DD);
    rope_kernel<<<(MM * HH * 16) / 256, blk, 0, stream>>>(q);
    rope_kernel<<<(MM * HH * 16) / 256, blk, 0, stream>>>(k);
    attn_kernel<false><<<gAtt, blk, 0, stream>>>(q, k, v, nullptr, attn);
    gemm_kernel<2><<<gD, blk, 0, stream>>>(attn, ca_wo, ca_bo, x1, x2, DD, DD);

    // --- FFN block ---
    rmsnorm_kernel<<<MM, blk, 0, stream>>>(x2, g3, xn);
    gemm_kernel<1><<<gF1, blk, 0, stream>>>(xn, ff_w1, ff_b1, nullptr, h, DD, FFF);
    gemm_kernel<2><<<gD, blk, 0, stream>>>(h, ff_w2, ff_b2, x2, out, FFF, DD);
}

// Round 2
// 1987.180 us; speedup vs baseline: 1.7275x; 1.7275x over previous
//
#include <hip/hip_runtime.h>
#include <hip/hip_bf16.h>
#include <math.h>

#define SS 1024
#define BB 4
#define DD 1024
#define HH 16
#define FFF 4096
#define MM (SS*BB)   // 4096 token rows

typedef __attribute__((ext_vector_type(8))) short bf16x8;
typedef __attribute__((ext_vector_type(4))) float f32x4;

// ---------------- RMSNorm: one block (256 thr) per row, bf16 out ----------------
__global__ void rmsnorm_kernel(const float* __restrict__ x, const float* __restrict__ g,
                               __hip_bfloat16* __restrict__ out) {
    int row = blockIdx.x;
    const float* xr = x + (size_t)row * DD;
    int tid = threadIdx.x;
    float4 v = *reinterpret_cast<const float4*>(xr + tid * 4);
    float ss = v.x*v.x + v.y*v.y + v.z*v.z + v.w*v.w;
    #pragma unroll
    for (int off = 32; off; off >>= 1) ss += __shfl_down(ss, off);
    __shared__ float part[4];
    if ((tid & 63) == 0) part[tid >> 6] = ss;
    __syncthreads();
    float tot = part[0] + part[1] + part[2] + part[3];
    float rms = sqrtf(tot) * (1.0f / 32.0f);      // ||x|| / sqrt(1024)
    float inv = 1.0f / (rms + 1e-8f);
    float4 gv = *reinterpret_cast<const float4*>(g + tid * 4);
    union { __hip_bfloat16 h[4]; uint2 u; } p;
    p.h[0] = __float2bfloat16(gv.x * v.x * inv);
    p.h[1] = __float2bfloat16(gv.y * v.y * inv);
    p.h[2] = __float2bfloat16(gv.z * v.z * inv);
    p.h[3] = __float2bfloat16(gv.w * v.w * inv);
    reinterpret_cast<uint2*>(out + (size_t)row * DD)[tid] = p.u;
}

// ---------------- fp32 -> bf16 elementwise ----------------
__global__ void f2b_kernel(const float* __restrict__ in, __hip_bfloat16* __restrict__ out) {
    int i = blockIdx.x * 256 + threadIdx.x;
    float4 v = reinterpret_cast<const float4*>(in)[i];
    union { __hip_bfloat16 h[4]; uint2 u; } p;
    p.h[0] = __float2bfloat16(v.x);
    p.h[1] = __float2bfloat16(v.y);
    p.h[2] = __float2bfloat16(v.z);
    p.h[3] = __float2bfloat16(v.w);
    reinterpret_cast<uint2*>(out)[i] = p.u;
}

// ---------------- transpose-convert: W[K,N] fp32 -> Wt[N,K] bf16 ----------------
__global__ void wtrans_kernel(const float* __restrict__ W, __hip_bfloat16* __restrict__ Wt,
                              int K, int N) {
    __shared__ float tile[32][33];
    int n0 = blockIdx.x * 32, k0 = blockIdx.y * 32;
    int tx = threadIdx.x & 31, ty = threadIdx.x >> 5;   // ty 0..7
    #pragma unroll
    for (int i = 0; i < 4; i++) {
        int kk = ty + i * 8;
        tile[kk][tx] = W[(size_t)(k0 + kk) * N + n0 + tx];
    }
    __syncthreads();
    #pragma unroll
    for (int i = 0; i < 4; i++) {
        int nn = ty + i * 8;
        Wt[(size_t)(n0 + nn) * K + k0 + tx] = __float2bfloat16(tile[tx][nn]);
    }
}

// ---------------- bf16 MFMA GEMM: C[M,N] = A[M,K] @ Bt[N,K]^T + bias ----------------
// m97 structure: 128x128 tile, BK=32, 4 waves (2x2), 4x4 16x16x32 fragments/wave,
// linear LDS + global_load_lds(16B), 2 barriers per k-step.
// EPI: 0 = bias -> fp32 ; 1 = bias+silu -> bf16 ; 2 = bias+residual -> fp32
template<int EPI>
__global__ __launch_bounds__(256) void gemm_bf16(
    const __hip_bfloat16* __restrict__ A, const __hip_bfloat16* __restrict__ Bt,
    const float* __restrict__ bias, const float* __restrict__ res,
    float* __restrict__ Cf, __hip_bfloat16* __restrict__ Cb, int K, int N)
{
    __shared__ __hip_bfloat16 As[128 * 32];
    __shared__ __hip_bfloat16 Bs[128 * 32];
    int tid = threadIdx.x;
    int lane = tid & 63, w = tid >> 6;
    int wr = w >> 1, wc = w & 1;
    int brow = blockIdx.y * 128, bcol = blockIdx.x * 128;

    f32x4 acc[4][4];
    #pragma unroll
    for (int m = 0; m < 4; m++)
        #pragma unroll
        for (int n = 0; n < 4; n++)
            acc[m][n] = (f32x4){0.f, 0.f, 0.f, 0.f};

    const __hip_bfloat16* Ab = A + (size_t)brow * K;
    const __hip_bfloat16* Bb = Bt + (size_t)bcol * K;

    for (int kt = 0; kt < K; kt += 32) {
        // stage 128x32 A-tile and B-tile; 512 chunks of 16B each per tile
        #pragma unroll
        for (int i = 0; i < 2; i++) {
            int f = i * 256 + tid;            // 0..511 (lane-contiguous within wave)
            int row = f >> 2, c8 = (f & 3) * 8;
            __builtin_amdgcn_global_load_lds(
                (const __attribute__((address_space(1))) void*)(Ab + (size_t)row * K + kt + c8),
                (__attribute__((address_space(3))) void*)(As + (size_t)(i * 256 + w * 64) * 8),
                16, 0, 0);
            __builtin_amdgcn_global_load_lds(
                (const __attribute__((address_space(1))) void*)(Bb + (size_t)row * K + kt + c8),
                (__attribute__((address_space(3))) void*)(Bs + (size_t)(i * 256 + w * 64) * 8),
                16, 0, 0);
        }
        __syncthreads();   // drains vmcnt before barrier

        int r = lane & 15, kg = (lane >> 4) * 8;
        bf16x8 aF[4], bF[4];
        #pragma unroll
        for (int m = 0; m < 4; m++)
            aF[m] = *reinterpret_cast<const bf16x8*>(As + (64 * wr + m * 16 + r) * 32 + kg);
        #pragma unroll
        for (int n = 0; n < 4; n++)
            bF[n] = *reinterpret_cast<const bf16x8*>(Bs + (64 * wc + n * 16 + r) * 32 + kg);
        #pragma unroll
        for (int m = 0; m < 4; m++)
            #pragma unroll
            for (int n = 0; n < 4; n++)
                acc[m][n] = __builtin_amdgcn_mfma_f32_16x16x32_bf16(aF[m], bF[n], acc[m][n], 0, 0, 0);
        __syncthreads();
    }

    // epilogue: C/D layout col = lane&15, row = (lane>>4)*4 + reg
    int row0 = brow + 64 * wr + (lane >> 4) * 4;
    int col0 = bcol + 64 * wc + (lane & 15);
    #pragma unroll
    for (int m = 0; m < 4; m++) {
        #pragma unroll
        for (int n = 0; n < 4; n++) {
            int ccol = col0 + n * 16;
            float bv = bias[ccol];
            #pragma unroll
            for (int q = 0; q < 4; q++) {
                int rrow = row0 + m * 16 + q;
                float o = acc[m][n][q] + bv;
                if (EPI == 1) {
                    o = o / (1.0f + __expf(-o));
                    Cb[(size_t)rrow * N + ccol] = __float2bfloat16(o);
                } else {
                    if (EPI == 2) o += res[(size_t)rrow * N + ccol];
                    Cf[(size_t)rrow * N + ccol] = o;
                }
            }
        }
    }
}

// ---------------- RoPE on first 32 dims of each 64-dim head ----------------
__global__ void rope_kernel(float* __restrict__ X) {
    int idx = blockIdx.x * 256 + threadIdx.x;   // M*H*16 total
    int pair = idx & 15;
    int hh = (idx >> 4) & 15;
    int row = idx >> 8;          // 0..M-1,  row = s*B + b
    int s = row >> 2;            // B = 4
    float inv = powf(10000.0f, -(float)pair / 16.0f);
    float ang = (float)s * inv;
    float c = cosf(ang), sn = sinf(ang);
    float* p = X + (size_t)row * DD + hh * 64 + pair * 2;
    float x0 = p[0], x1 = p[1];
    p[0] = x0 * c - x1 * sn;
    p[1] = x1 * c + x0 * sn;
}

// ---------------- Flash attention (fp32 SIMT), bf16 output ----------------
template<bool CAUSAL>
__global__ void attn_kernel(const float* __restrict__ Q, const float* __restrict__ K,
                            const float* __restrict__ V, const int* __restrict__ mask,
                            __hip_bfloat16* __restrict__ O) {
    __shared__ float Kt[64][65];
    __shared__ float Vt[64][65];
    __shared__ float Qs[16][65];
    __shared__ float Ps[4][4][68];
    int tid = threadIdx.x;
    int lane = tid & 63, w = tid >> 6;
    int bh = blockIdx.y;
    int b = bh >> 4, hh = bh & 15;
    int qb = blockIdx.x * 16;
    for (int idx = tid; idx < 16 * 64; idx += 256) {
        int r = idx >> 6, d = idx & 63;
        Qs[r][d] = Q[(size_t)((qb + r) * BB + b) * DD + hh * 64 + d] * 0.125f;
    }
    float m[4], l[4], o[4];
    #pragma unroll
    for (int r = 0; r < 4; r++) { m[r] = -1e38f; l[r] = 0.f; o[r] = 0.f; }
    int q0 = qb + w * 4;
    int ntiles = CAUSAL ? (qb >> 6) + 1 : (SS >> 6);
    for (int t = 0; t < ntiles; t++) {
        __syncthreads();
        for (int idx = tid; idx < 64 * 64; idx += 256) {
            int r = idx >> 6, d = idx & 63;
            Kt[r][d] = K[(size_t)((t * 64 + r) * BB + b) * DD + hh * 64 + d];
            Vt[r][d] = V[(size_t)((t * 64 + r) * BB + b) * DD + hh * 64 + d];
        }
        __syncthreads();
        float sc[4] = {0.f, 0.f, 0.f, 0.f};
        for (int d = 0; d < 64; d++) {
            float kv = Kt[lane][d];
            #pragma unroll
            for (int r = 0; r < 4; r++) sc[r] += Qs[w * 4 + r][d] * kv;
        }
        int key = t * 64 + lane;
        if (CAUSAL) {
            #pragma unroll
            for (int r = 0; r < 4; r++)
                if (mask[(size_t)(q0 + r) * SS + key] == 0) sc[r] = -1e9f;
        }
        #pragma unroll
        for (int r = 0; r < 4; r++) {
            float mx = sc[r];
            #pragma unroll
            for (int off = 32; off; off >>= 1) mx = fmaxf(mx, __shfl_xor(mx, off));
            float nm = fmaxf(m[r], mx);
            float alpha = __expf(m[r] - nm);
            float p = __expf(sc[r] - nm);
            float ps = p;
            #pragma unroll
            for (int off = 32; off; off >>= 1) ps += __shfl_xor(ps, off);
            l[r] = l[r] * alpha + ps;
            o[r] *= alpha;
            m[r] = nm;
            Ps[w][r][lane] = p;
        }
        for (int j = 0; j < 64; j++) {
            float vv = Vt[j][lane];
            #pragma unroll
            for (int r = 0; r < 4; r++) o[r] += Ps[w][r][j] * vv;
        }
    }
    #pragma unroll
    for (int r = 0; r < 4; r++)
        O[(size_t)((q0 + r) * BB + b) * DD + hh * 64 + lane] = __float2bfloat16(o[r] / l[r]);
}

extern "C" void kernel_launch(void* const* d_in, const int* in_sizes, int n_in,
                              void* d_out, int out_size, void* d_ws, size_t ws_size,
                              hipStream_t stream) {
    const float* x    = (const float*)d_in[0];
    const float* enc  = (const float*)d_in[1];
    const int*   mask = (const int*)d_in[2];
    const float* sa_wq = (const float*)d_in[3];
    const float* sa_bq = (const float*)d_in[4];
    const float* sa_wk = (const float*)d_in[5];
    const float* sa_bk = (const float*)d_in[6];
    const float* sa_wv = (const float*)d_in[7];
    const float* sa_bv = (const float*)d_in[8];
    const float* sa_wo = (const float*)d_in[9];
    const float* sa_bo = (const float*)d_in[10];
    const float* ca_wq = (const float*)d_in[11];
    const float* ca_bq = (const float*)d_in[12];
    const float* ca_wk = (const float*)d_in[13];
    const float* ca_bk = (const float*)d_in[14];
    const float* ca_wv = (const float*)d_in[15];
    const float* ca_bv = (const float*)d_in[16];
    const float* ca_wo = (const float*)d_in[17];
    const float* ca_bo = (const float*)d_in[18];
    const float* ff_w1 = (const float*)d_in[19];
    const float* ff_b1 = (const float*)d_in[20];
    const float* ff_w2 = (const float*)d_in[21];
    const float* ff_b2 = (const float*)d_in[22];
    const float* g1 = (const float*)d_in[23];
    const float* g2 = (const float*)d_in[24];
    const float* g3 = (const float*)d_in[25];
    float* out = (float*)d_out;

    // ---- workspace map (112 MB total) ----
    const size_t MB = 1024 * 1024;
    char* base = (char*)d_ws;
    __hip_bfloat16* sa_wqT = (__hip_bfloat16*)(base + 0 * MB);
    __hip_bfloat16* sa_wkT = (__hip_bfloat16*)(base + 2 * MB);
    __hip_bfloat16* sa_wvT = (__hip_bfloat16*)(base + 4 * MB);
    __hip_bfloat16* sa_woT = (__hip_bfloat16*)(base + 6 * MB);
    __hip_bfloat16* ca_wqT = (__hip_bfloat16*)(base + 8 * MB);
    __hip_bfloat16* ca_wkT = (__hip_bfloat16*)(base + 10 * MB);
    __hip_bfloat16* ca_wvT = (__hip_bfloat16*)(base + 12 * MB);
    __hip_bfloat16* ca_woT = (__hip_bfloat16*)(base + 14 * MB);
    __hip_bfloat16* w1T    = (__hip_bfloat16*)(base + 16 * MB);  // [FFF, DD]
    __hip_bfloat16* w2T    = (__hip_bfloat16*)(base + 24 * MB);  // [DD, FFF]
    __hip_bfloat16* xnb    = (__hip_bfloat16*)(base + 32 * MB);  // 8MB; doubles as attnb
    float* q  = (float*)(base + 40 * MB);                        // 16MB
    float* k  = (float*)(base + 56 * MB);                        // 16MB
    float* v  = (float*)(base + 72 * MB);                        // 16MB
    float* x1 = (float*)(base + 88 * MB);                        // 16MB
    float* x2 = (float*)(base + 40 * MB);                        // reuses q slot
    __hip_bfloat16* hb   = (__hip_bfloat16*)(base + 56 * MB);    // 32MB; reuses k,v
    __hip_bfloat16* encb = (__hip_bfloat16*)(base + 104 * MB);   // 8MB
    __hip_bfloat16* attnb = xnb;

    dim3 blk(256);
    dim3 gDD(32, 32);                   // wtrans D x D
    dim3 gW1(FFF / 32, DD / 32);        // wtrans [D,FF]
    dim3 gW2(DD / 32, FFF / 32);        // wtrans [FF,D]
    dim3 gGd(DD / 128, MM / 128);       // gemm N=1024
    dim3 gGf(FFF / 128, MM / 128);      // gemm N=4096
    dim3 gAtt(SS / 16, BB * HH);
    int ropeBlocks = (MM * HH * 16) / 256;

    // ---- one-time conversions ----
    wtrans_kernel<<<gDD, blk, 0, stream>>>(sa_wq, sa_wqT, DD, DD);
    wtrans_kernel<<<gDD, blk, 0, stream>>>(sa_wk, sa_wkT, DD, DD);
    wtrans_kernel<<<gDD, blk, 0, stream>>>(sa_wv, sa_wvT, DD, DD);
    wtrans_kernel<<<gDD, blk, 0, stream>>>(sa_wo, sa_woT, DD, DD);
    wtrans_kernel<<<gDD, blk, 0, stream>>>(ca_wq, ca_wqT, DD, DD);
    wtrans_kernel<<<gDD, blk, 0, stream>>>(ca_wk, ca_wkT, DD, DD);
    wtrans_kernel<<<gDD, blk, 0, stream>>>(ca_wv, ca_wvT, DD, DD);
    wtrans_kernel<<<gDD, blk, 0, stream>>>(ca_wo, ca_woT, DD, DD);
    wtrans_kernel<<<gW1, blk, 0, stream>>>(ff_w1, w1T, DD, FFF);
    wtrans_kernel<<<gW2, blk, 0, stream>>>(ff_w2, w2T, FFF, DD);
    f2b_kernel<<<(MM * DD / 4) / 256, blk, 0, stream>>>(enc, encb);

    // ---- self-attention block ----
    rmsnorm_kernel<<<MM, blk, 0, stream>>>(x, g1, xnb);
    gemm_bf16<0><<<gGd, blk, 0, stream>>>(xnb, sa_wqT, sa_bq, nullptr, q, nullptr, DD, DD);
    gemm_bf16<0><<<gGd, blk, 0, stream>>>(xnb, sa_wkT, sa_bk, nullptr, k, nullptr, DD, DD);
    gemm_bf16<0><<<gGd, blk, 0, stream>>>(xnb, sa_wvT, sa_bv, nullptr, v, nullptr, DD, DD);
    rope_kernel<<<ropeBlocks, blk, 0, stream>>>(q);
    rope_kernel<<<ropeBlocks, blk, 0, stream>>>(k);
    attn_kernel<true><<<gAtt, blk, 0, stream>>>(q, k, v, mask, attnb);
    gemm_bf16<2><<<gGd, blk, 0, stream>>>(attnb, sa_woT, sa_bo, x, x1, nullptr, DD, DD);

    // ---- cross-attention block ----
    rmsnorm_kernel<<<MM, blk, 0, stream>>>(x1, g2, xnb);
    gemm_bf16<0><<<gGd, blk, 0, stream>>>(xnb, ca_wqT, ca_bq, nullptr, q, nullptr, DD, DD);
    gemm_bf16<0><<<gGd, blk, 0, stream>>>(encb, ca_wkT, ca_bk, nullptr, k, nullptr, DD, DD);
    gemm_bf16<0><<<gGd, blk, 0, stream>>>(encb, ca_wvT, ca_bv, nullptr, v, nullptr, DD, DD);
    rope_kernel<<<ropeBlocks, blk, 0, stream>>>(q);
    rope_kernel<<<ropeBlocks, blk, 0, stream>>>(k);
    attn_kernel<false><<<gAtt, blk, 0, stream>>>(q, k, v, nullptr, attnb);
    gemm_bf16<2><<<gGd, blk, 0, stream>>>(attnb, ca_woT, ca_bo, x1, x2, nullptr, DD, DD);

    // ---- FFN block ----
    rmsnorm_kernel<<<MM, blk, 0, stream>>>(x2, g3, xnb);
    gemm_bf16<1><<<gGf, blk, 0, stream>>>(xnb, w1T, ff_b1, nullptr, nullptr, hb, DD, FFF);
    gemm_bf16<2><<<gGd, blk, 0, stream>>>(hb, w2T, ff_b2, x2, out, nullptr, FFF, DD);
}

// Round 3
// 595.751 us; speedup vs baseline: 5.7623x; 3.3356x over previous
//
#include <hip/hip_runtime.h>
#include <hip/hip_bf16.h>
#include <math.h>

#define SS 1024
#define BB 4
#define DD 1024
#define HH 16
#define FFF 4096
#define MM (SS*BB)   // 4096 token rows

typedef __attribute__((ext_vector_type(8))) short bf16x8;
typedef __attribute__((ext_vector_type(4))) float f32x4;

// ---------------- RMSNorm: one block (256 thr) per row, bf16 out ----------------
__global__ void rmsnorm_kernel(const float* __restrict__ x, const float* __restrict__ g,
                               __hip_bfloat16* __restrict__ out) {
    int row = blockIdx.x;
    const float* xr = x + (size_t)row * DD;
    int tid = threadIdx.x;
    float4 v = *reinterpret_cast<const float4*>(xr + tid * 4);
    float ss = v.x*v.x + v.y*v.y + v.z*v.z + v.w*v.w;
    #pragma unroll
    for (int off = 32; off; off >>= 1) ss += __shfl_down(ss, off);
    __shared__ float part[4];
    if ((tid & 63) == 0) part[tid >> 6] = ss;
    __syncthreads();
    float tot = part[0] + part[1] + part[2] + part[3];
    float rms = sqrtf(tot) * (1.0f / 32.0f);      // ||x|| / sqrt(1024)
    float inv = 1.0f / (rms + 1e-8f);
    float4 gv = *reinterpret_cast<const float4*>(g + tid * 4);
    union { __hip_bfloat16 h[4]; uint2 u; } p;
    p.h[0] = __float2bfloat16(gv.x * v.x * inv);
    p.h[1] = __float2bfloat16(gv.y * v.y * inv);
    p.h[2] = __float2bfloat16(gv.z * v.z * inv);
    p.h[3] = __float2bfloat16(gv.w * v.w * inv);
    reinterpret_cast<uint2*>(out + (size_t)row * DD)[tid] = p.u;
}

// ---------------- fp32 -> bf16 elementwise ----------------
__global__ void f2b_kernel(const float* __restrict__ in, __hip_bfloat16* __restrict__ out) {
    int i = blockIdx.x * 256 + threadIdx.x;
    float4 v = reinterpret_cast<const float4*>(in)[i];
    union { __hip_bfloat16 h[4]; uint2 u; } p;
    p.h[0] = __float2bfloat16(v.x);
    p.h[1] = __float2bfloat16(v.y);
    p.h[2] = __float2bfloat16(v.z);
    p.h[3] = __float2bfloat16(v.w);
    reinterpret_cast<uint2*>(out)[i] = p.u;
}

// ---------------- transpose-convert: W[K,N] fp32 -> Wt[N,K] bf16 ----------------
__global__ void wtrans_kernel(const float* __restrict__ W, __hip_bfloat16* __restrict__ Wt,
                              int K, int N) {
    __shared__ float tile[32][33];
    int n0 = blockIdx.x * 32, k0 = blockIdx.y * 32;
    int tx = threadIdx.x & 31, ty = threadIdx.x >> 5;   // ty 0..7
    #pragma unroll
    for (int i = 0; i < 4; i++) {
        int kk = ty + i * 8;
        tile[kk][tx] = W[(size_t)(k0 + kk) * N + n0 + tx];
    }
    __syncthreads();
    #pragma unroll
    for (int i = 0; i < 4; i++) {
        int nn = ty + i * 8;
        Wt[(size_t)(n0 + nn) * K + k0 + tx] = __float2bfloat16(tile[tx][nn]);
    }
}

// ---------------- bf16 MFMA GEMM: C[M,N] = A[M,K] @ Bt[N,K]^T + bias ----------------
// EPI: 0 = bias -> bf16 ; 1 = bias+silu -> bf16 ; 2 = bias+residual -> fp32
template<int EPI>
__global__ __launch_bounds__(256) void gemm_bf16(
    const __hip_bfloat16* __restrict__ A, const __hip_bfloat16* __restrict__ Bt,
    const float* __restrict__ bias, const float* __restrict__ res,
    float* __restrict__ Cf, __hip_bfloat16* __restrict__ Cb, int K, int N)
{
    __shared__ __hip_bfloat16 As[128 * 32];
    __shared__ __hip_bfloat16 Bs[128 * 32];
    int tid = threadIdx.x;
    int lane = tid & 63, w = tid >> 6;
    int wr = w >> 1, wc = w & 1;
    int brow = blockIdx.y * 128, bcol = blockIdx.x * 128;

    f32x4 acc[4][4];
    #pragma unroll
    for (int m = 0; m < 4; m++)
        #pragma unroll
        for (int n = 0; n < 4; n++)
            acc[m][n] = (f32x4){0.f, 0.f, 0.f, 0.f};

    const __hip_bfloat16* Ab = A + (size_t)brow * K;
    const __hip_bfloat16* Bb = Bt + (size_t)bcol * K;

    for (int kt = 0; kt < K; kt += 32) {
        #pragma unroll
        for (int i = 0; i < 2; i++) {
            int f = i * 256 + tid;
            int row = f >> 2, c8 = (f & 3) * 8;
            __builtin_amdgcn_global_load_lds(
                (const __attribute__((address_space(1))) void*)(Ab + (size_t)row * K + kt + c8),
                (__attribute__((address_space(3))) void*)(As + (size_t)(i * 256 + w * 64) * 8),
                16, 0, 0);
            __builtin_amdgcn_global_load_lds(
                (const __attribute__((address_space(1))) void*)(Bb + (size_t)row * K + kt + c8),
                (__attribute__((address_space(3))) void*)(Bs + (size_t)(i * 256 + w * 64) * 8),
                16, 0, 0);
        }
        __syncthreads();

        int r = lane & 15, kg = (lane >> 4) * 8;
        bf16x8 aF[4], bF[4];
        #pragma unroll
        for (int m = 0; m < 4; m++)
            aF[m] = *reinterpret_cast<const bf16x8*>(As + (64 * wr + m * 16 + r) * 32 + kg);
        #pragma unroll
        for (int n = 0; n < 4; n++)
            bF[n] = *reinterpret_cast<const bf16x8*>(Bs + (64 * wc + n * 16 + r) * 32 + kg);
        #pragma unroll
        for (int m = 0; m < 4; m++)
            #pragma unroll
            for (int n = 0; n < 4; n++)
                acc[m][n] = __builtin_amdgcn_mfma_f32_16x16x32_bf16(aF[m], bF[n], acc[m][n], 0, 0, 0);
        __syncthreads();
    }

    int row0 = brow + 64 * wr + ((lane >> 4) * 4);
    int col0 = bcol + 64 * wc + (lane & 15);
    #pragma unroll
    for (int m = 0; m < 4; m++) {
        #pragma unroll
        for (int n = 0; n < 4; n++) {
            int ccol = col0 + n * 16;
            float bv = bias[ccol];
            #pragma unroll
            for (int q = 0; q < 4; q++) {
                int rrow = row0 + m * 16 + q;
                float o = acc[m][n][q] + bv;
                if (EPI == 0) {
                    Cb[(size_t)rrow * N + ccol] = __float2bfloat16(o);
                } else if (EPI == 1) {
                    o = o / (1.0f + __expf(-o));
                    Cb[(size_t)rrow * N + ccol] = __float2bfloat16(o);
                } else {
                    o += res[(size_t)rrow * N + ccol];
                    Cf[(size_t)rrow * N + ccol] = o;
                }
            }
        }
    }
}

// ---------------- RoPE + relayout: [M][D] bf16 -> [B,H,S,64] bf16, optional scale ----------------
__global__ void rope_relayout(const __hip_bfloat16* __restrict__ Xn,
                              __hip_bfloat16* __restrict__ Xh, float scale) {
    int idx = blockIdx.x * 256 + threadIdx.x;    // M * 512 threads
    int pc = idx & 511;
    int row = idx >> 9;
    int d = pc * 2;
    int h = d >> 6, dh = d & 63;
    int s = row >> 2, b = row & 3;
    union { unsigned u; __hip_bfloat16 h2[2]; } cv;
    cv.u = *reinterpret_cast<const unsigned*>(Xn + (size_t)row * DD + d);
    float f0 = __bfloat162float(cv.h2[0]);
    float f1 = __bfloat162float(cv.h2[1]);
    if (dh < 32) {
        int p = dh >> 1;
        float ang = (float)s * __powf(10000.f, -(float)p * (1.0f / 16.0f));
        float c, sn;
        __sincosf(ang, &sn, &c);
        float r0 = f0 * c - f1 * sn;
        float r1 = f1 * c + f0 * sn;
        f0 = r0; f1 = r1;
    }
    cv.h2[0] = __float2bfloat16(f0 * scale);
    cv.h2[1] = __float2bfloat16(f1 * scale);
    *reinterpret_cast<unsigned*>(Xh + ((size_t)(b * HH + h) * SS + s) * 64 + dh) = cv.u;
}

// ---------------- V transpose: [M][D] bf16 -> [B,H,64,S] bf16 ----------------
__global__ void vtrans_kernel(const __hip_bfloat16* __restrict__ Vn,
                              __hip_bfloat16* __restrict__ Vt) {
    __shared__ __hip_bfloat16 t[64][72];
    int tid = threadIdx.x;
    int bh = blockIdx.y, b = bh >> 4, h = bh & 15;
    int s0 = blockIdx.x * 64;
    #pragma unroll
    for (int i = 0; i < 2; i++) {
        int f = tid + i * 256;
        int sr = f >> 3, c = (f & 7) * 8;
        *reinterpret_cast<uint4*>(&t[sr][c]) =
            *reinterpret_cast<const uint4*>(Vn + (size_t)((s0 + sr) * BB + b) * DD + h * 64 + c);
    }
    __syncthreads();
    #pragma unroll
    for (int i = 0; i < 2; i++) {
        int f = tid + i * 256;
        int d = f >> 3, c = (f & 7) * 8;
        __hip_bfloat16 tmp[8];
        #pragma unroll
        for (int j = 0; j < 8; j++) tmp[j] = t[c + j][d];
        *reinterpret_cast<uint4*>(Vt + ((size_t)bh * 64 + d) * SS + s0 + c) =
            *reinterpret_cast<uint4*>(tmp);
    }
}

// ---------------- MFMA flash attention ----------------
// Q,K: [B,H,S,64] bf16 (Q pre-scaled by 1/8, both roped). V: [B,H,64,S] bf16.
// Block: (qtile of 64 rows, b*H+h). 4 waves, wave w owns q rows [qb+16w, +16).
// KV tile = 64 keys, double-buffered LDS, XOR-swizzled chunks (both-sides).
template<bool CAUSAL>
__global__ __launch_bounds__(256) void attn_mfma(
    const __hip_bfloat16* __restrict__ Qh, const __hip_bfloat16* __restrict__ Kh,
    const __hip_bfloat16* __restrict__ Vth, __hip_bfloat16* __restrict__ O)
{
    __shared__ __hip_bfloat16 Ks[2][64 * 64];
    __shared__ __hip_bfloat16 Vs[2][64 * 64];
    __shared__ __hip_bfloat16 Ps[4][16][72];
    int tid = threadIdx.x, lane = tid & 63, w = tid >> 6;
    int r = lane & 15, g = lane >> 4;
    int bh = blockIdx.y;
    int b = bh >> 4, h = bh & 15;
    int qb = blockIdx.x * 64;
    const __hip_bfloat16* gQ = Qh + (size_t)bh * SS * 64;
    const __hip_bfloat16* gK = Kh + (size_t)bh * SS * 64;
    const __hip_bfloat16* gV = Vth + (size_t)bh * 64 * SS;

    // Q fragments (row = lane&15 -> q row qb+16w+r; k = g*8+j)
    bf16x8 qf0 = *reinterpret_cast<const bf16x8*>(gQ + (size_t)(qb + w * 16 + r) * 64 + g * 8);
    bf16x8 qf1 = *reinterpret_cast<const bf16x8*>(gQ + (size_t)(qb + w * 16 + r) * 64 + 32 + g * 8);

    f32x4 accO[4];
    float mreg[4], lreg[4];
    #pragma unroll
    for (int j = 0; j < 4; j++) {
        accO[j] = (f32x4){0.f, 0.f, 0.f, 0.f};
        mreg[j] = -1e38f; lreg[j] = 0.f;
    }

    int nt = CAUSAL ? (blockIdx.x + 1) : (SS / 64);

    auto stage = [&](int buf, int kt) {
        #pragma unroll
        for (int i = 0; i < 2; i++) {
            int f = i * 256 + tid;            // chunk id 0..511
            int row = f >> 3, cp = f & 7;
            int cs = cp ^ (row & 7);          // inverse-swizzled source chunk
            __builtin_amdgcn_global_load_lds(
                (const __attribute__((address_space(1))) void*)(gK + (size_t)(kt + row) * 64 + cs * 8),
                (__attribute__((address_space(3))) void*)(&Ks[buf][(i * 256 + w * 64) * 8]),
                16, 0, 0);
            __builtin_amdgcn_global_load_lds(
                (const __attribute__((address_space(1))) void*)(gV + (size_t)row * SS + kt + cs * 8),
                (__attribute__((address_space(3))) void*)(&Vs[buf][(i * 256 + w * 64) * 8]),
                16, 0, 0);
        }
    };

    stage(0, 0);
    __syncthreads();
    int cur = 0;
    for (int t = 0; t < nt; t++) {
        if (t + 1 < nt) stage(cur ^ 1, (t + 1) * 64);
        int kt = t * 64;

        // ---- S = Q K^T (scaled via Q) ----
        f32x4 sa[4];
        #pragma unroll
        for (int ks = 0; ks < 4; ks++) {
            sa[ks] = (f32x4){0.f, 0.f, 0.f, 0.f};
            int rk = ks * 16 + r;
            bf16x8 kf0 = *reinterpret_cast<const bf16x8*>(&Ks[cur][rk * 64 + ((g ^ (rk & 7)) * 8)]);
            bf16x8 kf1 = *reinterpret_cast<const bf16x8*>(&Ks[cur][rk * 64 + (((4 + g) ^ (rk & 7)) * 8)]);
            sa[ks] = __builtin_amdgcn_mfma_f32_16x16x32_bf16(qf0, kf0, sa[ks], 0, 0, 0);
            sa[ks] = __builtin_amdgcn_mfma_f32_16x16x32_bf16(qf1, kf1, sa[ks], 0, 0, 0);
        }

        // ---- causal mask (diagonal tile only) ----
        if (CAUSAL && t == nt - 1) {
            #pragma unroll
            for (int ks = 0; ks < 4; ks++) {
                int key = kt + ks * 16 + r;
                #pragma unroll
                for (int j = 0; j < 4; j++) {
                    int qq = qb + w * 16 + g * 4 + j;
                    if (key > qq) sa[ks][j] = -1e9f;
                }
            }
        }

        // ---- online softmax (rows = q, fully wave-parallel) ----
        #pragma unroll
        for (int j = 0; j < 4; j++) {
            float mx = fmaxf(fmaxf(sa[0][j], sa[1][j]), fmaxf(sa[2][j], sa[3][j]));
            mx = fmaxf(mx, __shfl_xor(mx, 1));
            mx = fmaxf(mx, __shfl_xor(mx, 2));
            mx = fmaxf(mx, __shfl_xor(mx, 4));
            mx = fmaxf(mx, __shfl_xor(mx, 8));
            float nm = fmaxf(mreg[j], mx);
            float alpha = __expf(mreg[j] - nm);
            mreg[j] = nm;
            float ps = 0.f;
            #pragma unroll
            for (int ks = 0; ks < 4; ks++) {
                float p = __expf(sa[ks][j] - nm);
                sa[ks][j] = p;
                ps += p;
            }
            ps += __shfl_xor(ps, 1);
            ps += __shfl_xor(ps, 2);
            ps += __shfl_xor(ps, 4);
            ps += __shfl_xor(ps, 8);
            lreg[j] = lreg[j] * alpha + ps;
            #pragma unroll
            for (int ds = 0; ds < 4; ds++) accO[ds][j] *= alpha;
        }

        // ---- P -> LDS (per-wave, padded) ----
        #pragma unroll
        for (int ks = 0; ks < 4; ks++)
            #pragma unroll
            for (int j = 0; j < 4; j++)
                Ps[w][g * 4 + j][ks * 16 + r] = __float2bfloat16(sa[ks][j]);

        // ---- O += P V ----
        #pragma unroll
        for (int ks2 = 0; ks2 < 2; ks2++) {
            bf16x8 pf = *reinterpret_cast<const bf16x8*>(&Ps[w][r][ks2 * 32 + g * 8]);
            #pragma unroll
            for (int ds = 0; ds < 4; ds++) {
                int rv = ds * 16 + r;
                bf16x8 vf = *reinterpret_cast<const bf16x8*>(
                    &Vs[cur][rv * 64 + (((ks2 * 4 + g) ^ (rv & 7)) * 8)]);
                accO[ds] = __builtin_amdgcn_mfma_f32_16x16x32_bf16(pf, vf, accO[ds], 0, 0, 0);
            }
        }
        cur ^= 1;
        __syncthreads();
    }

    // ---- epilogue: write natural [s*B+b][D] bf16 ----
    #pragma unroll
    for (int j = 0; j < 4; j++) {
        float inv = 1.0f / lreg[j];
        int s = qb + w * 16 + g * 4 + j;
        #pragma unroll
        for (int ds = 0; ds < 4; ds++)
            O[(size_t)(s * BB + b) * DD + h * 64 + ds * 16 + r] =
                __float2bfloat16(accO[ds][j] * inv);
    }
}

extern "C" void kernel_launch(void* const* d_in, const int* in_sizes, int n_in,
                              void* d_out, int out_size, void* d_ws, size_t ws_size,
                              hipStream_t stream) {
    const float* x    = (const float*)d_in[0];
    const float* enc  = (const float*)d_in[1];
    const float* sa_wq = (const float*)d_in[3];
    const float* sa_bq = (const float*)d_in[4];
    const float* sa_wk = (const float*)d_in[5];
    const float* sa_bk = (const float*)d_in[6];
    const float* sa_wv = (const float*)d_in[7];
    const float* sa_bv = (const float*)d_in[8];
    const float* sa_wo = (const float*)d_in[9];
    const float* sa_bo = (const float*)d_in[10];
    const float* ca_wq = (const float*)d_in[11];
    const float* ca_bq = (const float*)d_in[12];
    const float* ca_wk = (const float*)d_in[13];
    const float* ca_bk = (const float*)d_in[14];
    const float* ca_wv = (const float*)d_in[15];
    const float* ca_bv = (const float*)d_in[16];
    const float* ca_wo = (const float*)d_in[17];
    const float* ca_bo = (const float*)d_in[18];
    const float* ff_w1 = (const float*)d_in[19];
    const float* ff_b1 = (const float*)d_in[20];
    const float* ff_w2 = (const float*)d_in[21];
    const float* ff_b2 = (const float*)d_in[22];
    const float* g1 = (const float*)d_in[23];
    const float* g2 = (const float*)d_in[24];
    const float* g3 = (const float*)d_in[25];
    float* out = (float*)d_out;

    // ---- workspace map (112 MB) ----
    const size_t MB = 1024 * 1024;
    char* base = (char*)d_ws;
    __hip_bfloat16* sa_wqT = (__hip_bfloat16*)(base + 0 * MB);
    __hip_bfloat16* sa_wkT = (__hip_bfloat16*)(base + 2 * MB);
    __hip_bfloat16* sa_wvT = (__hip_bfloat16*)(base + 4 * MB);
    __hip_bfloat16* sa_woT = (__hip_bfloat16*)(base + 6 * MB);
    __hip_bfloat16* ca_wqT = (__hip_bfloat16*)(base + 8 * MB);
    __hip_bfloat16* ca_wkT = (__hip_bfloat16*)(base + 10 * MB);
    __hip_bfloat16* ca_wvT = (__hip_bfloat16*)(base + 12 * MB);
    __hip_bfloat16* ca_woT = (__hip_bfloat16*)(base + 14 * MB);
    __hip_bfloat16* w1T    = (__hip_bfloat16*)(base + 16 * MB);  // [FFF, DD]
    __hip_bfloat16* w2T    = (__hip_bfloat16*)(base + 24 * MB);  // [DD, FFF]
    __hip_bfloat16* xnb    = (__hip_bfloat16*)(base + 32 * MB);  // 8MB
    __hip_bfloat16* qn     = (__hip_bfloat16*)(base + 40 * MB);  // 8MB
    __hip_bfloat16* kn     = (__hip_bfloat16*)(base + 48 * MB);  // 8MB
    __hip_bfloat16* vn     = (__hip_bfloat16*)(base + 56 * MB);  // 8MB
    __hip_bfloat16* Qhp    = (__hip_bfloat16*)(base + 64 * MB);  // 8MB
    __hip_bfloat16* Khp    = (__hip_bfloat16*)(base + 72 * MB);  // 8MB
    __hip_bfloat16* Vtp    = (__hip_bfloat16*)(base + 80 * MB);  // 8MB
    __hip_bfloat16* attnb  = (__hip_bfloat16*)(base + 88 * MB);  // 8MB (also encb)
    __hip_bfloat16* encb   = attnb;
    float* x1 = (float*)(base + 96 * MB);                        // 16MB
    __hip_bfloat16* hb = (__hip_bfloat16*)(base + 40 * MB);      // 32MB @ FFN time

    dim3 blk(256);
    dim3 gDD(32, 32);
    dim3 gW1(FFF / 32, DD / 32);
    dim3 gW2(DD / 32, FFF / 32);
    dim3 gGd(DD / 128, MM / 128);
    dim3 gGf(FFF / 128, MM / 128);
    dim3 gAtt(SS / 64, BB * HH);
    dim3 gVt(SS / 64, BB * HH);
    int ropeBlocks = MM * 512 / 256;

    // ---- one-time conversions ----
    wtrans_kernel<<<gDD, blk, 0, stream>>>(sa_wq, sa_wqT, DD, DD);
    wtrans_kernel<<<gDD, blk, 0, stream>>>(sa_wk, sa_wkT, DD, DD);
    wtrans_kernel<<<gDD, blk, 0, stream>>>(sa_wv, sa_wvT, DD, DD);
    wtrans_kernel<<<gDD, blk, 0, stream>>>(sa_wo, sa_woT, DD, DD);
    wtrans_kernel<<<gDD, blk, 0, stream>>>(ca_wq, ca_wqT, DD, DD);
    wtrans_kernel<<<gDD, blk, 0, stream>>>(ca_wk, ca_wkT, DD, DD);
    wtrans_kernel<<<gDD, blk, 0, stream>>>(ca_wv, ca_wvT, DD, DD);
    wtrans_kernel<<<gDD, blk, 0, stream>>>(ca_wo, ca_woT, DD, DD);
    wtrans_kernel<<<gW1, blk, 0, stream>>>(ff_w1, w1T, DD, FFF);
    wtrans_kernel<<<gW2, blk, 0, stream>>>(ff_w2, w2T, FFF, DD);

    // ---- self-attention block ----
    rmsnorm_kernel<<<MM, blk, 0, stream>>>(x, g1, xnb);
    gemm_bf16<0><<<gGd, blk, 0, stream>>>(xnb, sa_wqT, sa_bq, nullptr, nullptr, qn, DD, DD);
    gemm_bf16<0><<<gGd, blk, 0, stream>>>(xnb, sa_wkT, sa_bk, nullptr, nullptr, kn, DD, DD);
    gemm_bf16<0><<<gGd, blk, 0, stream>>>(xnb, sa_wvT, sa_bv, nullptr, nullptr, vn, DD, DD);
    rope_relayout<<<ropeBlocks, blk, 0, stream>>>(qn, Qhp, 0.125f);
    rope_relayout<<<ropeBlocks, blk, 0, stream>>>(kn, Khp, 1.0f);
    vtrans_kernel<<<gVt, blk, 0, stream>>>(vn, Vtp);
    attn_mfma<true><<<gAtt, blk, 0, stream>>>(Qhp, Khp, Vtp, attnb);
    gemm_bf16<2><<<gGd, blk, 0, stream>>>(attnb, sa_woT, sa_bo, x, x1, nullptr, DD, DD);

    // ---- cross-attention block ----
    rmsnorm_kernel<<<MM, blk, 0, stream>>>(x1, g2, xnb);
    f2b_kernel<<<(MM * DD / 4) / 256, blk, 0, stream>>>(enc, encb);
    gemm_bf16<0><<<gGd, blk, 0, stream>>>(xnb, ca_wqT, ca_bq, nullptr, nullptr, qn, DD, DD);
    gemm_bf16<0><<<gGd, blk, 0, stream>>>(encb, ca_wkT, ca_bk, nullptr, nullptr, kn, DD, DD);
    gemm_bf16<0><<<gGd, blk, 0, stream>>>(encb, ca_wvT, ca_bv, nullptr, nullptr, vn, DD, DD);
    rope_relayout<<<ropeBlocks, blk, 0, stream>>>(qn, Qhp, 0.125f);
    rope_relayout<<<ropeBlocks, blk, 0, stream>>>(kn, Khp, 1.0f);
    vtrans_kernel<<<gVt, blk, 0, stream>>>(vn, Vtp);
    attn_mfma<false><<<gAtt, blk, 0, stream>>>(Qhp, Khp, Vtp, attnb);
    gemm_bf16<2><<<gGd, blk, 0, stream>>>(attnb, ca_woT, ca_bo, x1, x1, nullptr, DD, DD);

    // ---- FFN block ----
    rmsnorm_kernel<<<MM, blk, 0, stream>>>(x1, g3, xnb);
    gemm_bf16<1><<<gGf, blk, 0, stream>>>(xnb, w1T, ff_b1, nullptr, nullptr, hb, DD, FFF);
    gemm_bf16<2><<<gGd, blk, 0, stream>>>(hb, w2T, ff_b2, x1, out, nullptr, FFF, DD);
}

// Round 4
// 506.249 us; speedup vs baseline: 6.7810x; 1.1768x over previous
//
#include <hip/hip_runtime.h>
#include <hip/hip_bf16.h>
#include <math.h>

#define SS 1024
#define BB 4
#define DD 1024
#define HH 16
#define FFF 4096
#define MM (SS*BB)   // 4096 token rows

typedef __attribute__((ext_vector_type(8))) short bf16x8;
typedef __attribute__((ext_vector_type(4))) float f32x4;

// ---------------- RMSNorm: one block (256 thr) per row, bf16 out ----------------
__global__ void rmsnorm_kernel(const float* __restrict__ x, const float* __restrict__ g,
                               __hip_bfloat16* __restrict__ out) {
    int row = blockIdx.x;
    const float* xr = x + (size_t)row * DD;
    int tid = threadIdx.x;
    float4 v = *reinterpret_cast<const float4*>(xr + tid * 4);
    float ss = v.x*v.x + v.y*v.y + v.z*v.z + v.w*v.w;
    #pragma unroll
    for (int off = 32; off; off >>= 1) ss += __shfl_down(ss, off);
    __shared__ float part[4];
    if ((tid & 63) == 0) part[tid >> 6] = ss;
    __syncthreads();
    float tot = part[0] + part[1] + part[2] + part[3];
    float rms = sqrtf(tot) * (1.0f / 32.0f);
    float inv = 1.0f / (rms + 1e-8f);
    float4 gv = *reinterpret_cast<const float4*>(g + tid * 4);
    union { __hip_bfloat16 h[4]; uint2 u; } p;
    p.h[0] = __float2bfloat16(gv.x * v.x * inv);
    p.h[1] = __float2bfloat16(gv.y * v.y * inv);
    p.h[2] = __float2bfloat16(gv.z * v.z * inv);
    p.h[3] = __float2bfloat16(gv.w * v.w * inv);
    reinterpret_cast<uint2*>(out + (size_t)row * DD)[tid] = p.u;
}

// ---------------- fp32 -> bf16 elementwise ----------------
__global__ void f2b_kernel(const float* __restrict__ in, __hip_bfloat16* __restrict__ out) {
    int i = blockIdx.x * 256 + threadIdx.x;
    float4 v = reinterpret_cast<const float4*>(in)[i];
    union { __hip_bfloat16 h[4]; uint2 u; } p;
    p.h[0] = __float2bfloat16(v.x);
    p.h[1] = __float2bfloat16(v.y);
    p.h[2] = __float2bfloat16(v.z);
    p.h[3] = __float2bfloat16(v.w);
    reinterpret_cast<uint2*>(out)[i] = p.u;
}

// ---------------- bias concat (2 or 3 segments of n floats) ----------------
__global__ void bias_concat(const float* __restrict__ a, const float* __restrict__ b,
                            const float* __restrict__ c, float* __restrict__ o, int n) {
    int total = (c ? 3 : 2) * n;
    int i = blockIdx.x * 256 + threadIdx.x;
    if (i >= total) return;
    int seg = i / n, off = i - seg * n;
    const float* p = seg == 0 ? a : (seg == 1 ? b : c);
    o[i] = p[off];
}

// ---------------- transpose-convert: W[K,N] fp32 -> Wt[N,K] bf16 ----------------
__global__ void wtrans_kernel(const float* __restrict__ W, __hip_bfloat16* __restrict__ Wt,
                              int K, int N) {
    __shared__ float tile[32][33];
    int n0 = blockIdx.x * 32, k0 = blockIdx.y * 32;
    int tx = threadIdx.x & 31, ty = threadIdx.x >> 5;
    #pragma unroll
    for (int i = 0; i < 4; i++) {
        int kk = ty + i * 8;
        tile[kk][tx] = W[(size_t)(k0 + kk) * N + n0 + tx];
    }
    __syncthreads();
    #pragma unroll
    for (int i = 0; i < 4; i++) {
        int nn = ty + i * 8;
        Wt[(size_t)(n0 + nn) * K + k0 + tx] = __float2bfloat16(tile[tx][nn]);
    }
}

// ---------------- bf16 MFMA GEMM: C[M,N] = A[M,K] @ Bt[N,K]^T + bias ----------------
// BM=128, BN template (128 or 64), BK=32; 4 waves (2x2); XCD-swizzled blocks.
// EPI: 0 = bias -> bf16 ; 1 = bias+silu -> bf16 ; 2 = bias+residual -> fp32
template<int EPI, int BN>
__global__ __launch_bounds__(256) void gemm_bf16(
    const __hip_bfloat16* __restrict__ A, const __hip_bfloat16* __restrict__ Bt,
    const float* __restrict__ bias, const float* __restrict__ res,
    float* __restrict__ Cf, __hip_bfloat16* __restrict__ Cb, int K, int N)
{
    constexpr int NF = BN / 64;          // wave col-fragments: BN=128 -> 2? no:
    // wave tile = 64 rows x (BN/2) cols -> NF = BN/2/16
    constexpr int NFRAG = BN / 32;       // BN=128 -> 4, BN=64 -> 2
    __shared__ __hip_bfloat16 As[128 * 32];
    __shared__ __hip_bfloat16 Bs[BN * 32];
    int tid = threadIdx.x;
    int lane = tid & 63, w = tid >> 6;
    int wr = w >> 1, wc = w & 1;

    // bijective XCD-chunked swizzle (m204)
    int gx = gridDim.x;
    int nwg = gx * gridDim.y;
    int orig = blockIdx.y * gx + blockIdx.x;
    int qd = nwg >> 3, rr = nwg & 7, xcd = orig & 7, pos = orig >> 3;
    int lin = (xcd < rr ? xcd * (qd + 1) : rr * (qd + 1) + (xcd - rr) * qd) + pos;
    int brow = (lin / gx) * 128, bcol = (lin % gx) * BN;

    f32x4 acc[4][NFRAG];
    #pragma unroll
    for (int m = 0; m < 4; m++)
        #pragma unroll
        for (int n = 0; n < NFRAG; n++)
            acc[m][n] = (f32x4){0.f, 0.f, 0.f, 0.f};

    const __hip_bfloat16* Ab = A + (size_t)brow * K;
    const __hip_bfloat16* Bb = Bt + (size_t)bcol * K;

    for (int kt = 0; kt < K; kt += 32) {
        #pragma unroll
        for (int i = 0; i < 2; i++) {
            int f = i * 256 + tid;
            int row = f >> 2, c8 = (f & 3) * 8;
            __builtin_amdgcn_global_load_lds(
                (const __attribute__((address_space(1))) void*)(Ab + (size_t)row * K + kt + c8),
                (__attribute__((address_space(3))) void*)(As + (size_t)(i * 256 + w * 64) * 8),
                16, 0, 0);
        }
        #pragma unroll
        for (int i = 0; i < BN / 64; i++) {
            int f = i * 256 + tid;
            int row = f >> 2, c8 = (f & 3) * 8;
            __builtin_amdgcn_global_load_lds(
                (const __attribute__((address_space(1))) void*)(Bb + (size_t)row * K + kt + c8),
                (__attribute__((address_space(3))) void*)(Bs + (size_t)(i * 256 + w * 64) * 8),
                16, 0, 0);
        }
        __syncthreads();

        int r = lane & 15, kg = (lane >> 4) * 8;
        bf16x8 aF[4], bF[NFRAG];
        #pragma unroll
        for (int m = 0; m < 4; m++)
            aF[m] = *reinterpret_cast<const bf16x8*>(As + (64 * wr + m * 16 + r) * 32 + kg);
        #pragma unroll
        for (int n = 0; n < NFRAG; n++)
            bF[n] = *reinterpret_cast<const bf16x8*>(Bs + ((BN / 2) * wc + n * 16 + r) * 32 + kg);
        #pragma unroll
        for (int m = 0; m < 4; m++)
            #pragma unroll
            for (int n = 0; n < NFRAG; n++)
                acc[m][n] = __builtin_amdgcn_mfma_f32_16x16x32_bf16(aF[m], bF[n], acc[m][n], 0, 0, 0);
        __syncthreads();
    }

    int row0 = brow + 64 * wr + ((lane >> 4) * 4);
    int col0 = bcol + (BN / 2) * wc + (lane & 15);
    #pragma unroll
    for (int m = 0; m < 4; m++) {
        #pragma unroll
        for (int n = 0; n < NFRAG; n++) {
            int ccol = col0 + n * 16;
            float bv = bias[ccol];
            #pragma unroll
            for (int q = 0; q < 4; q++) {
                int rrow = row0 + m * 16 + q;
                float o = acc[m][n][q] + bv;
                if (EPI == 0) {
                    Cb[(size_t)rrow * N + ccol] = __float2bfloat16(o);
                } else if (EPI == 1) {
                    o = o / (1.0f + __expf(-o));
                    Cb[(size_t)rrow * N + ccol] = __float2bfloat16(o);
                } else {
                    o += res[(size_t)rrow * N + ccol];
                    Cf[(size_t)rrow * N + ccol] = o;
                }
            }
        }
    }
    (void)NF;
}

// ---------------- RoPE + relayout: [M][rowStride] bf16 -> [B,H,S,64] bf16 ----------------
__global__ void rope_relayout(const __hip_bfloat16* __restrict__ Xn, int rowStride,
                              __hip_bfloat16* __restrict__ Xh, float scale) {
    int idx = blockIdx.x * 256 + threadIdx.x;    // M * 512 threads
    int pc = idx & 511;
    int row = idx >> 9;
    int d = pc * 2;
    int h = d >> 6, dh = d & 63;
    int s = row >> 2, b = row & 3;
    union { unsigned u; __hip_bfloat16 h2[2]; } cv;
    cv.u = *reinterpret_cast<const unsigned*>(Xn + (size_t)row * rowStride + d);
    float f0 = __bfloat162float(cv.h2[0]);
    float f1 = __bfloat162float(cv.h2[1]);
    if (dh < 32) {
        int p = dh >> 1;
        float ang = (float)s * __powf(10000.f, -(float)p * (1.0f / 16.0f));
        float c, sn;
        __sincosf(ang, &sn, &c);
        float r0 = f0 * c - f1 * sn;
        float r1 = f1 * c + f0 * sn;
        f0 = r0; f1 = r1;
    }
    cv.h2[0] = __float2bfloat16(f0 * scale);
    cv.h2[1] = __float2bfloat16(f1 * scale);
    *reinterpret_cast<unsigned*>(Xh + ((size_t)(b * HH + h) * SS + s) * 64 + dh) = cv.u;
}

// ---------------- V transpose: [M][rowStride] bf16 -> [B,H,64,S] bf16 ----------------
__global__ void vtrans_kernel(const __hip_bfloat16* __restrict__ Vn, int rowStride,
                              __hip_bfloat16* __restrict__ Vt) {
    __shared__ __hip_bfloat16 t[64][72];
    int tid = threadIdx.x;
    int bh = blockIdx.y, b = bh >> 4, h = bh & 15;
    int s0 = blockIdx.x * 64;
    #pragma unroll
    for (int i = 0; i < 2; i++) {
        int f = tid + i * 256;
        int sr = f >> 3, c = (f & 7) * 8;
        *reinterpret_cast<uint4*>(&t[sr][c]) =
            *reinterpret_cast<const uint4*>(Vn + (size_t)((s0 + sr) * BB + b) * rowStride + h * 64 + c);
    }
    __syncthreads();
    #pragma unroll
    for (int i = 0; i < 2; i++) {
        int f = tid + i * 256;
        int d = f >> 3, c = (f & 7) * 8;
        __hip_bfloat16 tmp[8];
        #pragma unroll
        for (int j = 0; j < 8; j++) tmp[j] = t[c + j][d];
        *reinterpret_cast<uint4*>(Vt + ((size_t)bh * 64 + d) * SS + s0 + c) =
            *reinterpret_cast<uint4*>(tmp);
    }
}

// ---------------- MFMA flash attention (unchanged from round 3) ----------------
template<bool CAUSAL>
__global__ __launch_bounds__(256) void attn_mfma(
    const __hip_bfloat16* __restrict__ Qh, const __hip_bfloat16* __restrict__ Kh,
    const __hip_bfloat16* __restrict__ Vth, __hip_bfloat16* __restrict__ O)
{
    __shared__ __hip_bfloat16 Ks[2][64 * 64];
    __shared__ __hip_bfloat16 Vs[2][64 * 64];
    __shared__ __hip_bfloat16 Ps[4][16][72];
    int tid = threadIdx.x, lane = tid & 63, w = tid >> 6;
    int r = lane & 15, g = lane >> 4;
    int bh = blockIdx.y;
    int b = bh >> 4, h = bh & 15;
    int qb = blockIdx.x * 64;
    const __hip_bfloat16* gQ = Qh + (size_t)bh * SS * 64;
    const __hip_bfloat16* gK = Kh + (size_t)bh * SS * 64;
    const __hip_bfloat16* gV = Vth + (size_t)bh * 64 * SS;

    bf16x8 qf0 = *reinterpret_cast<const bf16x8*>(gQ + (size_t)(qb + w * 16 + r) * 64 + g * 8);
    bf16x8 qf1 = *reinterpret_cast<const bf16x8*>(gQ + (size_t)(qb + w * 16 + r) * 64 + 32 + g * 8);

    f32x4 accO[4];
    float mreg[4], lreg[4];
    #pragma unroll
    for (int j = 0; j < 4; j++) {
        accO[j] = (f32x4){0.f, 0.f, 0.f, 0.f};
        mreg[j] = -1e38f; lreg[j] = 0.f;
    }

    int nt = CAUSAL ? (blockIdx.x + 1) : (SS / 64);

    auto stage = [&](int buf, int kt) {
        #pragma unroll
        for (int i = 0; i < 2; i++) {
            int f = i * 256 + tid;
            int row = f >> 3, cp = f & 7;
            int cs = cp ^ (row & 7);
            __builtin_amdgcn_global_load_lds(
                (const __attribute__((address_space(1))) void*)(gK + (size_t)(kt + row) * 64 + cs * 8),
                (__attribute__((address_space(3))) void*)(&Ks[buf][(i * 256 + w * 64) * 8]),
                16, 0, 0);
            __builtin_amdgcn_global_load_lds(
                (const __attribute__((address_space(1))) void*)(gV + (size_t)row * SS + kt + cs * 8),
                (__attribute__((address_space(3))) void*)(&Vs[buf][(i * 256 + w * 64) * 8]),
                16, 0, 0);
        }
    };

    stage(0, 0);
    __syncthreads();
    int cur = 0;
    for (int t = 0; t < nt; t++) {
        if (t + 1 < nt) stage(cur ^ 1, (t + 1) * 64);
        int kt = t * 64;

        f32x4 sa[4];
        #pragma unroll
        for (int ks = 0; ks < 4; ks++) {
            sa[ks] = (f32x4){0.f, 0.f, 0.f, 0.f};
            int rk = ks * 16 + r;
            bf16x8 kf0 = *reinterpret_cast<const bf16x8*>(&Ks[cur][rk * 64 + ((g ^ (rk & 7)) * 8)]);
            bf16x8 kf1 = *reinterpret_cast<const bf16x8*>(&Ks[cur][rk * 64 + (((4 + g) ^ (rk & 7)) * 8)]);
            sa[ks] = __builtin_amdgcn_mfma_f32_16x16x32_bf16(qf0, kf0, sa[ks], 0, 0, 0);
            sa[ks] = __builtin_amdgcn_mfma_f32_16x16x32_bf16(qf1, kf1, sa[ks], 0, 0, 0);
        }

        if (CAUSAL && t == nt - 1) {
            #pragma unroll
            for (int ks = 0; ks < 4; ks++) {
                int key = kt + ks * 16 + r;
                #pragma unroll
                for (int j = 0; j < 4; j++) {
                    int qq = qb + w * 16 + g * 4 + j;
                    if (key > qq) sa[ks][j] = -1e9f;
                }
            }
        }

        #pragma unroll
        for (int j = 0; j < 4; j++) {
            float mx = fmaxf(fmaxf(sa[0][j], sa[1][j]), fmaxf(sa[2][j], sa[3][j]));
            mx = fmaxf(mx, __shfl_xor(mx, 1));
            mx = fmaxf(mx, __shfl_xor(mx, 2));
            mx = fmaxf(mx, __shfl_xor(mx, 4));
            mx = fmaxf(mx, __shfl_xor(mx, 8));
            float nm = fmaxf(mreg[j], mx);
            float alpha = __expf(mreg[j] - nm);
            mreg[j] = nm;
            float ps = 0.f;
            #pragma unroll
            for (int ks = 0; ks < 4; ks++) {
                float p = __expf(sa[ks][j] - nm);
                sa[ks][j] = p;
                ps += p;
            }
            ps += __shfl_xor(ps, 1);
            ps += __shfl_xor(ps, 2);
            ps += __shfl_xor(ps, 4);
            ps += __shfl_xor(ps, 8);
            lreg[j] = lreg[j] * alpha + ps;
            #pragma unroll
            for (int ds = 0; ds < 4; ds++) accO[ds][j] *= alpha;
        }

        #pragma unroll
        for (int ks = 0; ks < 4; ks++)
            #pragma unroll
            for (int j = 0; j < 4; j++)
                Ps[w][g * 4 + j][ks * 16 + r] = __float2bfloat16(sa[ks][j]);

        #pragma unroll
        for (int ks2 = 0; ks2 < 2; ks2++) {
            bf16x8 pf = *reinterpret_cast<const bf16x8*>(&Ps[w][r][ks2 * 32 + g * 8]);
            #pragma unroll
            for (int ds = 0; ds < 4; ds++) {
                int rv = ds * 16 + r;
                bf16x8 vf = *reinterpret_cast<const bf16x8*>(
                    &Vs[cur][rv * 64 + (((ks2 * 4 + g) ^ (rv & 7)) * 8)]);
                accO[ds] = __builtin_amdgcn_mfma_f32_16x16x32_bf16(pf, vf, accO[ds], 0, 0, 0);
            }
        }
        cur ^= 1;
        __syncthreads();
    }

    #pragma unroll
    for (int j = 0; j < 4; j++) {
        float inv = 1.0f / lreg[j];
        int s = qb + w * 16 + g * 4 + j;
        #pragma unroll
        for (int ds = 0; ds < 4; ds++)
            O[(size_t)(s * BB + b) * DD + h * 64 + ds * 16 + r] =
                __float2bfloat16(accO[ds][j] * inv);
    }
}

extern "C" void kernel_launch(void* const* d_in, const int* in_sizes, int n_in,
                              void* d_out, int out_size, void* d_ws, size_t ws_size,
                              hipStream_t stream) {
    const float* x    = (const float*)d_in[0];
    const float* enc  = (const float*)d_in[1];
    const float* sa_wq = (const float*)d_in[3];
    const float* sa_bq = (const float*)d_in[4];
    const float* sa_wk = (const float*)d_in[5];
    const float* sa_bk = (const float*)d_in[6];
    const float* sa_wv = (const float*)d_in[7];
    const float* sa_bv = (const float*)d_in[8];
    const float* sa_wo = (const float*)d_in[9];
    const float* sa_bo = (const float*)d_in[10];
    const float* ca_wq = (const float*)d_in[11];
    const float* ca_bq = (const float*)d_in[12];
    const float* ca_wk = (const float*)d_in[13];
    const float* ca_bk = (const float*)d_in[14];
    const float* ca_wv = (const float*)d_in[15];
    const float* ca_bv = (const float*)d_in[16];
    const float* ca_wo = (const float*)d_in[17];
    const float* ca_bo = (const float*)d_in[18];
    const float* ff_w1 = (const float*)d_in[19];
    const float* ff_b1 = (const float*)d_in[20];
    const float* ff_w2 = (const float*)d_in[21];
    const float* ff_b2 = (const float*)d_in[22];
    const float* g1 = (const float*)d_in[23];
    const float* g2 = (const float*)d_in[24];
    const float* g3 = (const float*)d_in[25];
    float* out = (float*)d_out;

    // ---- workspace map (112 MB) ----
    const size_t MB = 1024 * 1024;
    char* base = (char*)d_ws;
    __hip_bfloat16* sa_qkvT = (__hip_bfloat16*)(base + 0 * MB);   // [3072][1024] 6MB
    __hip_bfloat16* sa_woT  = (__hip_bfloat16*)(base + 6 * MB);   // 2MB
    __hip_bfloat16* ca_wqT  = (__hip_bfloat16*)(base + 8 * MB);   // 2MB
    __hip_bfloat16* ca_kvT  = (__hip_bfloat16*)(base + 10 * MB);  // [2048][1024] 4MB
    __hip_bfloat16* ca_woT  = (__hip_bfloat16*)(base + 14 * MB);  // 2MB
    __hip_bfloat16* w1T     = (__hip_bfloat16*)(base + 16 * MB);  // [FFF][DD] 8MB
    __hip_bfloat16* w2T     = (__hip_bfloat16*)(base + 24 * MB);  // [DD][FFF] 8MB
    float* sa_bqkv = (float*)(base + 32 * MB);                    // 3072 f
    float* ca_bkv  = (float*)(base + 32 * MB + 16384);            // 2048 f
    __hip_bfloat16* xnb   = (__hip_bfloat16*)(base + 33 * MB);    // 8MB (also attnb)
    __hip_bfloat16* qkv   = (__hip_bfloat16*)(base + 41 * MB);    // [M][3072] 24MB
    __hip_bfloat16* Qhp   = (__hip_bfloat16*)(base + 65 * MB);    // 8MB (also encb)
    __hip_bfloat16* Khp   = (__hip_bfloat16*)(base + 73 * MB);    // 8MB
    __hip_bfloat16* Vtp   = (__hip_bfloat16*)(base + 81 * MB);    // 8MB
    float* x1 = (float*)(base + 96 * MB);                         // 16MB -> 112
    __hip_bfloat16* attnb = xnb;
    __hip_bfloat16* encb  = Qhp;
    __hip_bfloat16* qn    = qkv;                                  // CA: [M][1024] 8MB
    __hip_bfloat16* kvb   = qkv + (size_t)4 * MB;                 // CA: [M][2048] 16MB
    __hip_bfloat16* hb    = qkv;                                  // FFN: [M][FFF] 32MB (41..73)

    dim3 blk(256);
    dim3 gDD(32, 32);
    dim3 gW1(FFF / 32, DD / 32);
    dim3 gW2(DD / 32, FFF / 32);
    dim3 gQKV(3072 / 128, MM / 128);   // 24 x 32 = 768
    dim3 gKV(2048 / 128, MM / 128);    // 16 x 32 = 512
    dim3 gN64(DD / 64, MM / 128);      // 16 x 32 = 512
    dim3 gF1(FFF / 128, MM / 128);     // 32 x 32 = 1024
    dim3 gAtt(SS / 64, BB * HH);
    int ropeBlocks = MM * 512 / 256;

    // ---- one-time conversions ----
    wtrans_kernel<<<gDD, blk, 0, stream>>>(sa_wq, sa_qkvT, DD, DD);
    wtrans_kernel<<<gDD, blk, 0, stream>>>(sa_wk, sa_qkvT + (size_t)1024 * DD, DD, DD);
    wtrans_kernel<<<gDD, blk, 0, stream>>>(sa_wv, sa_qkvT + (size_t)2048 * DD, DD, DD);
    wtrans_kernel<<<gDD, blk, 0, stream>>>(sa_wo, sa_woT, DD, DD);
    wtrans_kernel<<<gDD, blk, 0, stream>>>(ca_wq, ca_wqT, DD, DD);
    wtrans_kernel<<<gDD, blk, 0, stream>>>(ca_wk, ca_kvT, DD, DD);
    wtrans_kernel<<<gDD, blk, 0, stream>>>(ca_wv, ca_kvT + (size_t)1024 * DD, DD, DD);
    wtrans_kernel<<<gDD, blk, 0, stream>>>(ca_wo, ca_woT, DD, DD);
    wtrans_kernel<<<gW1, blk, 0, stream>>>(ff_w1, w1T, DD, FFF);
    wtrans_kernel<<<gW2, blk, 0, stream>>>(ff_w2, w2T, FFF, DD);
    bias_concat<<<12, blk, 0, stream>>>(sa_bq, sa_bk, sa_bv, sa_bqkv, DD);
    bias_concat<<<8, blk, 0, stream>>>(ca_bk, ca_bv, nullptr, ca_bkv, DD);

    // ---- self-attention block ----
    rmsnorm_kernel<<<MM, blk, 0, stream>>>(x, g1, xnb);
    gemm_bf16<0, 128><<<gQKV, blk, 0, stream>>>(xnb, sa_qkvT, sa_bqkv, nullptr, nullptr, qkv, DD, 3072);
    rope_relayout<<<ropeBlocks, blk, 0, stream>>>(qkv, 3072, Qhp, 0.125f);
    rope_relayout<<<ropeBlocks, blk, 0, stream>>>(qkv + 1024, 3072, Khp, 1.0f);
    vtrans_kernel<<<gAtt, blk, 0, stream>>>(qkv + 2048, 3072, Vtp);
    attn_mfma<true><<<gAtt, blk, 0, stream>>>(Qhp, Khp, Vtp, attnb);
    gemm_bf16<2, 64><<<gN64, blk, 0, stream>>>(attnb, sa_woT, sa_bo, x, x1, nullptr, DD, DD);

    // ---- cross-attention block ----
    rmsnorm_kernel<<<MM, blk, 0, stream>>>(x1, g2, xnb);
    f2b_kernel<<<(MM * DD / 4) / 256, blk, 0, stream>>>(enc, encb);
    gemm_bf16<0, 128><<<gKV, blk, 0, stream>>>(encb, ca_kvT, ca_bkv, nullptr, nullptr, kvb, DD, 2048);
    gemm_bf16<0, 64><<<gN64, blk, 0, stream>>>(xnb, ca_wqT, ca_bq, nullptr, nullptr, qn, DD, DD);
    rope_relayout<<<ropeBlocks, blk, 0, stream>>>(qn, 1024, Qhp, 0.125f);
    rope_relayout<<<ropeBlocks, blk, 0, stream>>>(kvb, 2048, Khp, 1.0f);
    vtrans_kernel<<<gAtt, blk, 0, stream>>>(kvb + 1024, 2048, Vtp);
    attn_mfma<false><<<gAtt, blk, 0, stream>>>(Qhp, Khp, Vtp, attnb);
    gemm_bf16<2, 64><<<gN64, blk, 0, stream>>>(attnb, ca_woT, ca_bo, x1, x1, nullptr, DD, DD);

    // ---- FFN block ----
    rmsnorm_kernel<<<MM, blk, 0, stream>>>(x1, g3, xnb);
    gemm_bf16<1, 128><<<gF1, blk, 0, stream>>>(xnb, w1T, ff_b1, nullptr, nullptr, hb, DD, FFF);
    gemm_bf16<2, 64><<<gN64, blk, 0, stream>>>(hb, w2T, ff_b2, x1, out, nullptr, FFF, DD);
}

// Round 5
// 476.277 us; speedup vs baseline: 7.2077x; 1.0629x over previous
//
#include <hip/hip_runtime.h>
#include <hip/hip_bf16.h>
#include <math.h>

#define SS 1024
#define BB 4
#define DD 1024
#define HH 16
#define FFF 4096
#define MM (SS*BB)   // 4096 token rows

typedef __attribute__((ext_vector_type(8))) short bf16x8;
typedef __attribute__((ext_vector_type(4))) float f32x4;

// ---------------- RMSNorm: one block (256 thr) per row, bf16 out ----------------
__global__ void rmsnorm_kernel(const float* __restrict__ x, const float* __restrict__ g,
                               __hip_bfloat16* __restrict__ out) {
    int row = blockIdx.x;
    const float* xr = x + (size_t)row * DD;
    int tid = threadIdx.x;
    float4 v = *reinterpret_cast<const float4*>(xr + tid * 4);
    float ss = v.x*v.x + v.y*v.y + v.z*v.z + v.w*v.w;
    #pragma unroll
    for (int off = 32; off; off >>= 1) ss += __shfl_down(ss, off);
    __shared__ float part[4];
    if ((tid & 63) == 0) part[tid >> 6] = ss;
    __syncthreads();
    float tot = part[0] + part[1] + part[2] + part[3];
    float rms = sqrtf(tot) * (1.0f / 32.0f);
    float inv = 1.0f / (rms + 1e-8f);
    float4 gv = *reinterpret_cast<const float4*>(g + tid * 4);
    union { __hip_bfloat16 h[4]; uint2 u; } p;
    p.h[0] = __float2bfloat16(gv.x * v.x * inv);
    p.h[1] = __float2bfloat16(gv.y * v.y * inv);
    p.h[2] = __float2bfloat16(gv.z * v.z * inv);
    p.h[3] = __float2bfloat16(gv.w * v.w * inv);
    reinterpret_cast<uint2*>(out + (size_t)row * DD)[tid] = p.u;
}

// ---------------- fp32 -> bf16 elementwise ----------------
__global__ void f2b_kernel(const float* __restrict__ in, __hip_bfloat16* __restrict__ out) {
    int i = blockIdx.x * 256 + threadIdx.x;
    float4 v = reinterpret_cast<const float4*>(in)[i];
    union { __hip_bfloat16 h[4]; uint2 u; } p;
    p.h[0] = __float2bfloat16(v.x);
    p.h[1] = __float2bfloat16(v.y);
    p.h[2] = __float2bfloat16(v.z);
    p.h[3] = __float2bfloat16(v.w);
    reinterpret_cast<uint2*>(out)[i] = p.u;
}

// ---------------- bias concat (2 or 3 segments of n floats) ----------------
__global__ void bias_concat(const float* __restrict__ a, const float* __restrict__ b,
                            const float* __restrict__ c, float* __restrict__ o, int n) {
    int total = (c ? 3 : 2) * n;
    int i = blockIdx.x * 256 + threadIdx.x;
    if (i >= total) return;
    int seg = i / n, off = i - seg * n;
    const float* p = seg == 0 ? a : (seg == 1 ? b : c);
    o[i] = p[off];
}

// ---------------- batched transpose-convert: 8x W[1024,1024] fp32 -> Wt[1024,1024] bf16 ----------------
__global__ void wtrans8_kernel(const float* s0, const float* s1, const float* s2, const float* s3,
                               const float* s4, const float* s5, const float* s6, const float* s7,
                               __hip_bfloat16* d0, __hip_bfloat16* d1, __hip_bfloat16* d2,
                               __hip_bfloat16* d3, __hip_bfloat16* d4, __hip_bfloat16* d5,
                               __hip_bfloat16* d6, __hip_bfloat16* d7) {
    const float* W; __hip_bfloat16* Wt;
    switch (blockIdx.z) {
        case 0: W = s0; Wt = d0; break;
        case 1: W = s1; Wt = d1; break;
        case 2: W = s2; Wt = d2; break;
        case 3: W = s3; Wt = d3; break;
        case 4: W = s4; Wt = d4; break;
        case 5: W = s5; Wt = d5; break;
        case 6: W = s6; Wt = d6; break;
        default: W = s7; Wt = d7; break;
    }
    __shared__ float tile[32][33];
    int n0 = blockIdx.x * 32, k0 = blockIdx.y * 32;
    int tx = threadIdx.x & 31, ty = threadIdx.x >> 5;
    #pragma unroll
    for (int i = 0; i < 4; i++) {
        int kk = ty + i * 8;
        tile[kk][tx] = W[(size_t)(k0 + kk) * DD + n0 + tx];
    }
    __syncthreads();
    #pragma unroll
    for (int i = 0; i < 4; i++) {
        int nn = ty + i * 8;
        Wt[(size_t)(n0 + nn) * DD + k0 + tx] = __float2bfloat16(tile[tx][nn]);
    }
}

// ---------------- transpose-convert: W[K,N] fp32 -> Wt[N,K] bf16 ----------------
__global__ void wtrans_kernel(const float* __restrict__ W, __hip_bfloat16* __restrict__ Wt,
                              int K, int N) {
    __shared__ float tile[32][33];
    int n0 = blockIdx.x * 32, k0 = blockIdx.y * 32;
    int tx = threadIdx.x & 31, ty = threadIdx.x >> 5;
    #pragma unroll
    for (int i = 0; i < 4; i++) {
        int kk = ty + i * 8;
        tile[kk][tx] = W[(size_t)(k0 + kk) * N + n0 + tx];
    }
    __syncthreads();
    #pragma unroll
    for (int i = 0; i < 4; i++) {
        int nn = ty + i * 8;
        Wt[(size_t)(n0 + nn) * K + k0 + tx] = __float2bfloat16(tile[tx][nn]);
    }
}

// ---------------- bf16 MFMA GEMM: C[M,N] = A[M,K] @ Bt[N,K]^T + bias ----------------
// BM=128, BN template (128 or 64), BK=32; 4 waves (2x2); XCD-swizzled blocks.
// T3 minimum 2-phase: LDS double-buffer, stage(t+1) issued BEFORE compute(t);
// single __syncthreads per k-step (its implicit vmcnt(0) drain lands after MFMA).
// EPI: 0 = bias -> bf16 ; 1 = bias+silu -> bf16 ; 2 = bias+residual -> fp32
template<int EPI, int BN>
__global__ __launch_bounds__(256) void gemm_bf16(
    const __hip_bfloat16* __restrict__ A, const __hip_bfloat16* __restrict__ Bt,
    const float* __restrict__ bias, const float* __restrict__ res,
    float* __restrict__ Cf, __hip_bfloat16* __restrict__ Cb, int K, int N)
{
    constexpr int NFRAG = BN / 32;       // BN=128 -> 4, BN=64 -> 2
    __shared__ __hip_bfloat16 As[2][128 * 32];
    __shared__ __hip_bfloat16 Bs[2][BN * 32];
    int tid = threadIdx.x;
    int lane = tid & 63, w = tid >> 6;
    int wr = w >> 1, wc = w & 1;

    // bijective XCD-chunked swizzle (m204)
    int gx = gridDim.x;
    int nwg = gx * gridDim.y;
    int orig = blockIdx.y * gx + blockIdx.x;
    int qd = nwg >> 3, rr = nwg & 7, xcd = orig & 7, pos = orig >> 3;
    int lin = (xcd < rr ? xcd * (qd + 1) : rr * (qd + 1) + (xcd - rr) * qd) + pos;
    int brow = (lin / gx) * 128, bcol = (lin % gx) * BN;

    f32x4 acc[4][NFRAG];
    #pragma unroll
    for (int m = 0; m < 4; m++)
        #pragma unroll
        for (int n = 0; n < NFRAG; n++)
            acc[m][n] = (f32x4){0.f, 0.f, 0.f, 0.f};

    const __hip_bfloat16* Ab = A + (size_t)brow * K;
    const __hip_bfloat16* Bb = Bt + (size_t)bcol * K;

    auto stage = [&](int buf, int kt) {
        #pragma unroll
        for (int i = 0; i < 2; i++) {
            int f = i * 256 + tid;
            int row = f >> 2, c8 = (f & 3) * 8;
            __builtin_amdgcn_global_load_lds(
                (const __attribute__((address_space(1))) void*)(Ab + (size_t)row * K + kt + c8),
                (__attribute__((address_space(3))) void*)(As[buf] + (size_t)(i * 256 + w * 64) * 8),
                16, 0, 0);
        }
        #pragma unroll
        for (int i = 0; i < BN / 64; i++) {
            int f = i * 256 + tid;
            int row = f >> 2, c8 = (f & 3) * 8;
            __builtin_amdgcn_global_load_lds(
                (const __attribute__((address_space(1))) void*)(Bb + (size_t)row * K + kt + c8),
                (__attribute__((address_space(3))) void*)(Bs[buf] + (size_t)(i * 256 + w * 64) * 8),
                16, 0, 0);
        }
    };

    int nt = K >> 5;
    stage(0, 0);
    __syncthreads();     // drain prologue loads
    int cur = 0;
    for (int t = 0; t < nt; t++) {
        if (t + 1 < nt) stage(cur ^ 1, (t + 1) << 5);   // prefetch flies under MFMA

        int r = lane & 15, kg = (lane >> 4) * 8;
        bf16x8 aF[4], bF[NFRAG];
        #pragma unroll
        for (int m = 0; m < 4; m++)
            aF[m] = *reinterpret_cast<const bf16x8*>(As[cur] + (64 * wr + m * 16 + r) * 32 + kg);
        #pragma unroll
        for (int n = 0; n < NFRAG; n++)
            bF[n] = *reinterpret_cast<const bf16x8*>(Bs[cur] + ((BN / 2) * wc + n * 16 + r) * 32 + kg);
        #pragma unroll
        for (int m = 0; m < 4; m++)
            #pragma unroll
            for (int n = 0; n < NFRAG; n++)
                acc[m][n] = __builtin_amdgcn_mfma_f32_16x16x32_bf16(aF[m], bF[n], acc[m][n], 0, 0, 0);

        __syncthreads();   // waits prefetch completion + everyone done reading cur
        cur ^= 1;
    }

    int row0 = brow + 64 * wr + ((lane >> 4) * 4);
    int col0 = bcol + (BN / 2) * wc + (lane & 15);
    #pragma unroll
    for (int m = 0; m < 4; m++) {
        #pragma unroll
        for (int n = 0; n < NFRAG; n++) {
            int ccol = col0 + n * 16;
            float bv = bias[ccol];
            #pragma unroll
            for (int q = 0; q < 4; q++) {
                int rrow = row0 + m * 16 + q;
                float o = acc[m][n][q] + bv;
                if (EPI == 0) {
                    Cb[(size_t)rrow * N + ccol] = __float2bfloat16(o);
                } else if (EPI == 1) {
                    o = o / (1.0f + __expf(-o));
                    Cb[(size_t)rrow * N + ccol] = __float2bfloat16(o);
                } else {
                    o += res[(size_t)rrow * N + ccol];
                    Cf[(size_t)rrow * N + ccol] = o;
                }
            }
        }
    }
}

// ---------------- RoPE + relayout: [M][rowStride] bf16 -> [B,H,S,64] bf16 ----------------
__global__ void rope_relayout(const __hip_bfloat16* __restrict__ Xn, int rowStride,
                              __hip_bfloat16* __restrict__ Xh, float scale) {
    int idx = blockIdx.x * 256 + threadIdx.x;    // M * 512 threads
    int pc = idx & 511;
    int row = idx >> 9;
    int d = pc * 2;
    int h = d >> 6, dh = d & 63;
    int s = row >> 2, b = row & 3;
    union { unsigned u; __hip_bfloat16 h2[2]; } cv;
    cv.u = *reinterpret_cast<const unsigned*>(Xn + (size_t)row * rowStride + d);
    float f0 = __bfloat162float(cv.h2[0]);
    float f1 = __bfloat162float(cv.h2[1]);
    if (dh < 32) {
        int p = dh >> 1;
        float ang = (float)s * __powf(10000.f, -(float)p * (1.0f / 16.0f));
        float c, sn;
        __sincosf(ang, &sn, &c);
        float r0 = f0 * c - f1 * sn;
        float r1 = f1 * c + f0 * sn;
        f0 = r0; f1 = r1;
    }
    cv.h2[0] = __float2bfloat16(f0 * scale);
    cv.h2[1] = __float2bfloat16(f1 * scale);
    *reinterpret_cast<unsigned*>(Xh + ((size_t)(b * HH + h) * SS + s) * 64 + dh) = cv.u;
}

// ---------------- V transpose: [M][rowStride] bf16 -> [B,H,64,S] bf16 ----------------
__global__ void vtrans_kernel(const __hip_bfloat16* __restrict__ Vn, int rowStride,
                              __hip_bfloat16* __restrict__ Vt) {
    __shared__ __hip_bfloat16 t[64][72];
    int tid = threadIdx.x;
    int bh = blockIdx.y, b = bh >> 4, h = bh & 15;
    int s0 = blockIdx.x * 64;
    #pragma unroll
    for (int i = 0; i < 2; i++) {
        int f = tid + i * 256;
        int sr = f >> 3, c = (f & 7) * 8;
        *reinterpret_cast<uint4*>(&t[sr][c]) =
            *reinterpret_cast<const uint4*>(Vn + (size_t)((s0 + sr) * BB + b) * rowStride + h * 64 + c);
    }
    __syncthreads();
    #pragma unroll
    for (int i = 0; i < 2; i++) {
        int f = tid + i * 256;
        int d = f >> 3, c = (f & 7) * 8;
        __hip_bfloat16 tmp[8];
        #pragma unroll
        for (int j = 0; j < 8; j++) tmp[j] = t[c + j][d];
        *reinterpret_cast<uint4*>(Vt + ((size_t)bh * 64 + d) * SS + s0 + c) =
            *reinterpret_cast<uint4*>(tmp);
    }
}

// ---------------- MFMA flash attention ----------------
template<bool CAUSAL>
__global__ __launch_bounds__(256) void attn_mfma(
    const __hip_bfloat16* __restrict__ Qh, const __hip_bfloat16* __restrict__ Kh,
    const __hip_bfloat16* __restrict__ Vth, __hip_bfloat16* __restrict__ O)
{
    __shared__ __hip_bfloat16 Ks[2][64 * 64];
    __shared__ __hip_bfloat16 Vs[2][64 * 64];
    __shared__ __hip_bfloat16 Ps[4][16][72];
    int tid = threadIdx.x, lane = tid & 63, w = tid >> 6;
    int r = lane & 15, g = lane >> 4;
    int bh = blockIdx.y;
    int b = bh >> 4, h = bh & 15;
    int qb = blockIdx.x * 64;
    const __hip_bfloat16* gQ = Qh + (size_t)bh * SS * 64;
    const __hip_bfloat16* gK = Kh + (size_t)bh * SS * 64;
    const __hip_bfloat16* gV = Vth + (size_t)bh * 64 * SS;

    bf16x8 qf0 = *reinterpret_cast<const bf16x8*>(gQ + (size_t)(qb + w * 16 + r) * 64 + g * 8);
    bf16x8 qf1 = *reinterpret_cast<const bf16x8*>(gQ + (size_t)(qb + w * 16 + r) * 64 + 32 + g * 8);

    f32x4 accO[4];
    float mreg[4], lreg[4];
    #pragma unroll
    for (int j = 0; j < 4; j++) {
        accO[j] = (f32x4){0.f, 0.f, 0.f, 0.f};
        mreg[j] = -1e38f; lreg[j] = 0.f;
    }

    int nt = CAUSAL ? (blockIdx.x + 1) : (SS / 64);

    auto stage = [&](int buf, int kt) {
        #pragma unroll
        for (int i = 0; i < 2; i++) {
            int f = i * 256 + tid;
            int row = f >> 3, cp = f & 7;
            int cs = cp ^ (row & 7);
            __builtin_amdgcn_global_load_lds(
                (const __attribute__((address_space(1))) void*)(gK + (size_t)(kt + row) * 64 + cs * 8),
                (__attribute__((address_space(3))) void*)(&Ks[buf][(i * 256 + w * 64) * 8]),
                16, 0, 0);
            __builtin_amdgcn_global_load_lds(
                (const __attribute__((address_space(1))) void*)(gV + (size_t)row * SS + kt + cs * 8),
                (__attribute__((address_space(3))) void*)(&Vs[buf][(i * 256 + w * 64) * 8]),
                16, 0, 0);
        }
    };

    stage(0, 0);
    __syncthreads();
    int cur = 0;
    for (int t = 0; t < nt; t++) {
        if (t + 1 < nt) stage(cur ^ 1, (t + 1) * 64);
        int kt = t * 64;

        f32x4 sa[4];
        #pragma unroll
        for (int ks = 0; ks < 4; ks++) {
            sa[ks] = (f32x4){0.f, 0.f, 0.f, 0.f};
            int rk = ks * 16 + r;
            bf16x8 kf0 = *reinterpret_cast<const bf16x8*>(&Ks[cur][rk * 64 + ((g ^ (rk & 7)) * 8)]);
            bf16x8 kf1 = *reinterpret_cast<const bf16x8*>(&Ks[cur][rk * 64 + (((4 + g) ^ (rk & 7)) * 8)]);
            sa[ks] = __builtin_amdgcn_mfma_f32_16x16x32_bf16(qf0, kf0, sa[ks], 0, 0, 0);
            sa[ks] = __builtin_amdgcn_mfma_f32_16x16x32_bf16(qf1, kf1, sa[ks], 0, 0, 0);
        }

        if (CAUSAL && t == nt - 1) {
            #pragma unroll
            for (int ks = 0; ks < 4; ks++) {
                int key = kt + ks * 16 + r;
                #pragma unroll
                for (int j = 0; j < 4; j++) {
                    int qq = qb + w * 16 + g * 4 + j;
                    if (key > qq) sa[ks][j] = -1e9f;
                }
            }
        }

        #pragma unroll
        for (int j = 0; j < 4; j++) {
            float mx = fmaxf(fmaxf(sa[0][j], sa[1][j]), fmaxf(sa[2][j], sa[3][j]));
            mx = fmaxf(mx, __shfl_xor(mx, 1));
            mx = fmaxf(mx, __shfl_xor(mx, 2));
            mx = fmaxf(mx, __shfl_xor(mx, 4));
            mx = fmaxf(mx, __shfl_xor(mx, 8));
            float nm = fmaxf(mreg[j], mx);
            float alpha = __expf(mreg[j] - nm);
            mreg[j] = nm;
            float ps = 0.f;
            #pragma unroll
            for (int ks = 0; ks < 4; ks++) {
                float p = __expf(sa[ks][j] - nm);
                sa[ks][j] = p;
                ps += p;
            }
            ps += __shfl_xor(ps, 1);
            ps += __shfl_xor(ps, 2);
            ps += __shfl_xor(ps, 4);
            ps += __shfl_xor(ps, 8);
            lreg[j] = lreg[j] * alpha + ps;
            #pragma unroll
            for (int ds = 0; ds < 4; ds++) accO[ds][j] *= alpha;
        }

        #pragma unroll
        for (int ks = 0; ks < 4; ks++)
            #pragma unroll
            for (int j = 0; j < 4; j++)
                Ps[w][g * 4 + j][ks * 16 + r] = __float2bfloat16(sa[ks][j]);

        #pragma unroll
        for (int ks2 = 0; ks2 < 2; ks2++) {
            bf16x8 pf = *reinterpret_cast<const bf16x8*>(&Ps[w][r][ks2 * 32 + g * 8]);
            #pragma unroll
            for (int ds = 0; ds < 4; ds++) {
                int rv = ds * 16 + r;
                bf16x8 vf = *reinterpret_cast<const bf16x8*>(
                    &Vs[cur][rv * 64 + (((ks2 * 4 + g) ^ (rv & 7)) * 8)]);
                accO[ds] = __builtin_amdgcn_mfma_f32_16x16x32_bf16(pf, vf, accO[ds], 0, 0, 0);
            }
        }
        cur ^= 1;
        __syncthreads();
    }

    #pragma unroll
    for (int j = 0; j < 4; j++) {
        float inv = 1.0f / lreg[j];
        int s = qb + w * 16 + g * 4 + j;
        #pragma unroll
        for (int ds = 0; ds < 4; ds++)
            O[(size_t)(s * BB + b) * DD + h * 64 + ds * 16 + r] =
                __float2bfloat16(accO[ds][j] * inv);
    }
}

extern "C" void kernel_launch(void* const* d_in, const int* in_sizes, int n_in,
                              void* d_out, int out_size, void* d_ws, size_t ws_size,
                              hipStream_t stream) {
    const float* x    = (const float*)d_in[0];
    const float* enc  = (const float*)d_in[1];
    const float* sa_wq = (const float*)d_in[3];
    const float* sa_bq = (const float*)d_in[4];
    const float* sa_wk = (const float*)d_in[5];
    const float* sa_bk = (const float*)d_in[6];
    const float* sa_wv = (const float*)d_in[7];
    const float* sa_bv = (const float*)d_in[8];
    const float* sa_wo = (const float*)d_in[9];
    const float* sa_bo = (const float*)d_in[10];
    const float* ca_wq = (const float*)d_in[11];
    const float* ca_bq = (const float*)d_in[12];
    const float* ca_wk = (const float*)d_in[13];
    const float* ca_bk = (const float*)d_in[14];
    const float* ca_wv = (const float*)d_in[15];
    const float* ca_bv = (const float*)d_in[16];
    const float* ca_wo = (const float*)d_in[17];
    const float* ca_bo = (const float*)d_in[18];
    const float* ff_w1 = (const float*)d_in[19];
    const float* ff_b1 = (const float*)d_in[20];
    const float* ff_w2 = (const float*)d_in[21];
    const float* ff_b2 = (const float*)d_in[22];
    const float* g1 = (const float*)d_in[23];
    const float* g2 = (const float*)d_in[24];
    const float* g3 = (const float*)d_in[25];
    float* out = (float*)d_out;

    // ---- workspace map (112 MB) ----
    const size_t MB = 1024 * 1024;
    char* base = (char*)d_ws;
    __hip_bfloat16* sa_qkvT = (__hip_bfloat16*)(base + 0 * MB);   // [3072][1024] 6MB
    __hip_bfloat16* sa_woT  = (__hip_bfloat16*)(base + 6 * MB);   // 2MB
    __hip_bfloat16* ca_wqT  = (__hip_bfloat16*)(base + 8 * MB);   // 2MB
    __hip_bfloat16* ca_kvT  = (__hip_bfloat16*)(base + 10 * MB);  // [2048][1024] 4MB
    __hip_bfloat16* ca_woT  = (__hip_bfloat16*)(base + 14 * MB);  // 2MB
    __hip_bfloat16* w1T     = (__hip_bfloat16*)(base + 16 * MB);  // [FFF][DD] 8MB
    __hip_bfloat16* w2T     = (__hip_bfloat16*)(base + 24 * MB);  // [DD][FFF] 8MB
    float* sa_bqkv = (float*)(base + 32 * MB);                    // 3072 f
    float* ca_bkv  = (float*)(base + 32 * MB + 16384);            // 2048 f
    __hip_bfloat16* xnb   = (__hip_bfloat16*)(base + 33 * MB);    // 8MB (also attnb)
    __hip_bfloat16* qkv   = (__hip_bfloat16*)(base + 41 * MB);    // [M][3072] 24MB
    __hip_bfloat16* Qhp   = (__hip_bfloat16*)(base + 65 * MB);    // 8MB (also encb)
    __hip_bfloat16* Khp   = (__hip_bfloat16*)(base + 73 * MB);    // 8MB
    __hip_bfloat16* Vtp   = (__hip_bfloat16*)(base + 81 * MB);    // 8MB
    float* x1 = (float*)(base + 96 * MB);                         // 16MB -> 112
    __hip_bfloat16* attnb = xnb;
    __hip_bfloat16* encb  = Qhp;
    __hip_bfloat16* qn    = qkv;                                  // CA: [M][1024] 8MB
    __hip_bfloat16* kvb   = qkv + (size_t)4 * MB;                 // CA: [M][2048] 16MB
    __hip_bfloat16* hb    = qkv;                                  // FFN: [M][FFF] 32MB (41..73)

    dim3 blk(256);
    dim3 gT8(32, 32, 8);
    dim3 gW1(FFF / 32, DD / 32);
    dim3 gW2(DD / 32, FFF / 32);
    dim3 gQKV(3072 / 128, MM / 128);   // 24 x 32 = 768
    dim3 gKV(2048 / 128, MM / 128);    // 16 x 32 = 512
    dim3 gN64(DD / 64, MM / 128);      // 16 x 32 = 512
    dim3 gF1(FFF / 128, MM / 128);     // 32 x 32 = 1024
    dim3 gAtt(SS / 64, BB * HH);
    int ropeBlocks = MM * 512 / 256;

    // ---- one-time conversions ----
    wtrans8_kernel<<<gT8, blk, 0, stream>>>(
        sa_wq, sa_wk, sa_wv, sa_wo, ca_wq, ca_wk, ca_wv, ca_wo,
        sa_qkvT, sa_qkvT + (size_t)1024 * DD, sa_qkvT + (size_t)2048 * DD, sa_woT,
        ca_wqT, ca_kvT, ca_kvT + (size_t)1024 * DD, ca_woT);
    wtrans_kernel<<<gW1, blk, 0, stream>>>(ff_w1, w1T, DD, FFF);
    wtrans_kernel<<<gW2, blk, 0, stream>>>(ff_w2, w2T, FFF, DD);
    bias_concat<<<12, blk, 0, stream>>>(sa_bq, sa_bk, sa_bv, sa_bqkv, DD);
    bias_concat<<<8, blk, 0, stream>>>(ca_bk, ca_bv, nullptr, ca_bkv, DD);

    // ---- self-attention block ----
    rmsnorm_kernel<<<MM, blk, 0, stream>>>(x, g1, xnb);
    gemm_bf16<0, 128><<<gQKV, blk, 0, stream>>>(xnb, sa_qkvT, sa_bqkv, nullptr, nullptr, qkv, DD, 3072);
    rope_relayout<<<ropeBlocks, blk, 0, stream>>>(qkv, 3072, Qhp, 0.125f);
    rope_relayout<<<ropeBlocks, blk, 0, stream>>>(qkv + 1024, 3072, Khp, 1.0f);
    vtrans_kernel<<<gAtt, blk, 0, stream>>>(qkv + 2048, 3072, Vtp);
    attn_mfma<true><<<gAtt, blk, 0, stream>>>(Qhp, Khp, Vtp, attnb);
    gemm_bf16<2, 64><<<gN64, blk, 0, stream>>>(attnb, sa_woT, sa_bo, x, x1, nullptr, DD, DD);

    // ---- cross-attention block ----
    rmsnorm_kernel<<<MM, blk, 0, stream>>>(x1, g2, xnb);
    f2b_kernel<<<(MM * DD / 4) / 256, blk, 0, stream>>>(enc, encb);
    gemm_bf16<0, 128><<<gKV, blk, 0, stream>>>(encb, ca_kvT, ca_bkv, nullptr, nullptr, kvb, DD, 2048);
    gemm_bf16<0, 64><<<gN64, blk, 0, stream>>>(xnb, ca_wqT, ca_bq, nullptr, nullptr, qn, DD, DD);
    rope_relayout<<<ropeBlocks, blk, 0, stream>>>(qn, 1024, Qhp, 0.125f);
    rope_relayout<<<ropeBlocks, blk, 0, stream>>>(kvb, 2048, Khp, 1.0f);
    vtrans_kernel<<<gAtt, blk, 0, stream>>>(kvb + 1024, 2048, Vtp);
    attn_mfma<false><<<gAtt, blk, 0, stream>>>(Qhp, Khp, Vtp, attnb);
    gemm_bf16<2, 64><<<gN64, blk, 0, stream>>>(attnb, ca_woT, ca_bo, x1, x1, nullptr, DD, DD);

    // ---- FFN block ----
    rmsnorm_kernel<<<MM, blk, 0, stream>>>(x1, g3, xnb);
    gemm_bf16<1, 128><<<gF1, blk, 0, stream>>>(xnb, w1T, ff_b1, nullptr, nullptr, hb, DD, FFF);
    gemm_bf16<2, 64><<<gN64, blk, 0, stream>>>(hb, w2T, ff_b2, x1, out, nullptr, FFF, DD);
}

// Round 6
// 463.072 us; speedup vs baseline: 7.4133x; 1.0285x over previous
//
#include <hip/hip_runtime.h>
#include <hip/hip_bf16.h>
#include <math.h>

#define SS 1024
#define BB 4
#define DD 1024
#define HH 16
#define FFF 4096
#define MM (SS*BB)   // 4096 token rows

typedef __attribute__((ext_vector_type(8))) short bf16x8;
typedef __attribute__((ext_vector_type(4))) float f32x4;

#define VM_WAIT(n) asm volatile("s_waitcnt vmcnt(" #n ")" ::: "memory")
#define MEM_FENCE() asm volatile("" ::: "memory")

// ---------------- RMSNorm: one block (256 thr) per row, bf16 out ----------------
__global__ void rmsnorm_kernel(const float* __restrict__ x, const float* __restrict__ g,
                               __hip_bfloat16* __restrict__ out) {
    int row = blockIdx.x;
    const float* xr = x + (size_t)row * DD;
    int tid = threadIdx.x;
    float4 v = *reinterpret_cast<const float4*>(xr + tid * 4);
    float ss = v.x*v.x + v.y*v.y + v.z*v.z + v.w*v.w;
    #pragma unroll
    for (int off = 32; off; off >>= 1) ss += __shfl_down(ss, off);
    __shared__ float part[4];
    if ((tid & 63) == 0) part[tid >> 6] = ss;
    __syncthreads();
    float tot = part[0] + part[1] + part[2] + part[3];
    float rms = sqrtf(tot) * (1.0f / 32.0f);
    float inv = 1.0f / (rms + 1e-8f);
    float4 gv = *reinterpret_cast<const float4*>(g + tid * 4);
    union { __hip_bfloat16 h[4]; uint2 u; } p;
    p.h[0] = __float2bfloat16(gv.x * v.x * inv);
    p.h[1] = __float2bfloat16(gv.y * v.y * inv);
    p.h[2] = __float2bfloat16(gv.z * v.z * inv);
    p.h[3] = __float2bfloat16(gv.w * v.w * inv);
    reinterpret_cast<uint2*>(out + (size_t)row * DD)[tid] = p.u;
}

// ---------------- fp32 -> bf16 elementwise ----------------
__global__ void f2b_kernel(const float* __restrict__ in, __hip_bfloat16* __restrict__ out) {
    int i = blockIdx.x * 256 + threadIdx.x;
    float4 v = reinterpret_cast<const float4*>(in)[i];
    union { __hip_bfloat16 h[4]; uint2 u; } p;
    p.h[0] = __float2bfloat16(v.x);
    p.h[1] = __float2bfloat16(v.y);
    p.h[2] = __float2bfloat16(v.z);
    p.h[3] = __float2bfloat16(v.w);
    reinterpret_cast<uint2*>(out)[i] = p.u;
}

// ---------------- bias concat (2 or 3 segments of n floats) ----------------
__global__ void bias_concat(const float* __restrict__ a, const float* __restrict__ b,
                            const float* __restrict__ c, float* __restrict__ o, int n) {
    int total = (c ? 3 : 2) * n;
    int i = blockIdx.x * 256 + threadIdx.x;
    if (i >= total) return;
    int seg = i / n, off = i - seg * n;
    const float* p = seg == 0 ? a : (seg == 1 ? b : c);
    o[i] = p[off];
}

// ---------------- batched transpose-convert: 8x W[1024,1024] fp32 -> Wt bf16 ----------------
__global__ void wtrans8_kernel(const float* s0, const float* s1, const float* s2, const float* s3,
                               const float* s4, const float* s5, const float* s6, const float* s7,
                               __hip_bfloat16* d0, __hip_bfloat16* d1, __hip_bfloat16* d2,
                               __hip_bfloat16* d3, __hip_bfloat16* d4, __hip_bfloat16* d5,
                               __hip_bfloat16* d6, __hip_bfloat16* d7) {
    const float* W; __hip_bfloat16* Wt;
    switch (blockIdx.z) {
        case 0: W = s0; Wt = d0; break;
        case 1: W = s1; Wt = d1; break;
        case 2: W = s2; Wt = d2; break;
        case 3: W = s3; Wt = d3; break;
        case 4: W = s4; Wt = d4; break;
        case 5: W = s5; Wt = d5; break;
        case 6: W = s6; Wt = d6; break;
        default: W = s7; Wt = d7; break;
    }
    __shared__ float tile[32][33];
    int n0 = blockIdx.x * 32, k0 = blockIdx.y * 32;
    int tx = threadIdx.x & 31, ty = threadIdx.x >> 5;
    #pragma unroll
    for (int i = 0; i < 4; i++) {
        int kk = ty + i * 8;
        tile[kk][tx] = W[(size_t)(k0 + kk) * DD + n0 + tx];
    }
    __syncthreads();
    #pragma unroll
    for (int i = 0; i < 4; i++) {
        int nn = ty + i * 8;
        Wt[(size_t)(n0 + nn) * DD + k0 + tx] = __float2bfloat16(tile[tx][nn]);
    }
}

// ---------------- transpose-convert: W[K,N] fp32 -> Wt[N,K] bf16 ----------------
__global__ void wtrans_kernel(const float* __restrict__ W, __hip_bfloat16* __restrict__ Wt,
                              int K, int N) {
    __shared__ float tile[32][33];
    int n0 = blockIdx.x * 32, k0 = blockIdx.y * 32;
    int tx = threadIdx.x & 31, ty = threadIdx.x >> 5;
    #pragma unroll
    for (int i = 0; i < 4; i++) {
        int kk = ty + i * 8;
        tile[kk][tx] = W[(size_t)(k0 + kk) * N + n0 + tx];
    }
    __syncthreads();
    #pragma unroll
    for (int i = 0; i < 4; i++) {
        int nn = ty + i * 8;
        Wt[(size_t)(n0 + nn) * K + k0 + tx] = __float2bfloat16(tile[tx][nn]);
    }
}

// ---------------- bf16 MFMA GEMM: C[M,N] = A[M,K] @ Bt[N,K]^T + bias ----------------
// BM=128, BN in {64,128}, BK=32; 4 waves (2x2); XCD-swizzled blocks.
// T4 pipeline: DEPTH-deep LDS multi-buffer, raw s_barrier + counted vmcnt
// (never drains to 0 mid-loop) so prefetch loads stay in flight across barriers.
// Per-thread loads per stage: L = 2 + BN/64 (A:2, B:BN/64).
// EPI: 0 = bias -> bf16 ; 1 = bias+silu -> bf16 ; 2 = bias+residual -> fp32
template<int EPI, int BN>
__global__ __launch_bounds__(256) void gemm_bf16(
    const __hip_bfloat16* __restrict__ A, const __hip_bfloat16* __restrict__ Bt,
    const float* __restrict__ bias, const float* __restrict__ res,
    float* __restrict__ Cf, __hip_bfloat16* __restrict__ Cb, int K, int N)
{
    constexpr int NFRAG = BN / 32;            // BN=128 -> 4, BN=64 -> 2
    constexpr int DEPTH = (BN == 64) ? 4 : 3; // both = 48KB LDS
    __shared__ __hip_bfloat16 As[DEPTH][128 * 32];
    __shared__ __hip_bfloat16 Bs[DEPTH][BN * 32];
    int tid = threadIdx.x;
    int lane = tid & 63, w = tid >> 6;
    int wr = w >> 1, wc = w & 1;

    // bijective XCD-chunked swizzle (m204)
    int gx = gridDim.x;
    int nwg = gx * gridDim.y;
    int orig = blockIdx.y * gx + blockIdx.x;
    int qd = nwg >> 3, rr = nwg & 7, xcd = orig & 7, pos = orig >> 3;
    int lin = (xcd < rr ? xcd * (qd + 1) : rr * (qd + 1) + (xcd - rr) * qd) + pos;
    int brow = (lin / gx) * 128, bcol = (lin % gx) * BN;

    f32x4 acc[4][NFRAG];
    #pragma unroll
    for (int m = 0; m < 4; m++)
        #pragma unroll
        for (int n = 0; n < NFRAG; n++)
            acc[m][n] = (f32x4){0.f, 0.f, 0.f, 0.f};

    const __hip_bfloat16* Ab = A + (size_t)brow * K;
    const __hip_bfloat16* Bb = Bt + (size_t)bcol * K;

    auto stage = [&](int buf, int kt) {
        #pragma unroll
        for (int i = 0; i < 2; i++) {
            int f = i * 256 + tid;
            int row = f >> 2, c8 = (f & 3) * 8;
            __builtin_amdgcn_global_load_lds(
                (const __attribute__((address_space(1))) void*)(Ab + (size_t)row * K + kt + c8),
                (__attribute__((address_space(3))) void*)(As[buf] + (size_t)(i * 256 + w * 64) * 8),
                16, 0, 0);
        }
        #pragma unroll
        for (int i = 0; i < BN / 64; i++) {
            int f = i * 256 + tid;
            int row = f >> 2, c8 = (f & 3) * 8;
            __builtin_amdgcn_global_load_lds(
                (const __attribute__((address_space(1))) void*)(Bb + (size_t)row * K + kt + c8),
                (__attribute__((address_space(3))) void*)(Bs[buf] + (size_t)(i * 256 + w * 64) * 8),
                16, 0, 0);
        }
    };

    int nt = K >> 5;                    // K >= 1024 -> nt >= 32 >= DEPTH
    #pragma unroll
    for (int d = 0; d < DEPTH; d++) stage(d, d << 5);

    int cb = 0;
    for (int t = 0; t < nt; t++) {
        int inflight = nt - 1 - t;
        if (inflight > DEPTH - 1) inflight = DEPTH - 1;
        // wait: tile t's L loads complete; newer stages stay in flight
        if constexpr (BN == 64) {       // L=3, DEPTH=4
            if (inflight == 3) VM_WAIT(9);
            else if (inflight == 2) VM_WAIT(6);
            else if (inflight == 1) VM_WAIT(3);
            else VM_WAIT(0);
        } else {                        // L=4, DEPTH=3
            if (inflight == 2) VM_WAIT(8);
            else if (inflight == 1) VM_WAIT(4);
            else VM_WAIT(0);
        }
        __builtin_amdgcn_s_barrier();   // all waves' tile-t loads now visible
        MEM_FENCE();                    // keep LDS reads below the barrier

        int r = lane & 15, kg = (lane >> 4) * 8;
        bf16x8 aF[4], bF[NFRAG];
        #pragma unroll
        for (int m = 0; m < 4; m++)
            aF[m] = *reinterpret_cast<const bf16x8*>(As[cb] + (64 * wr + m * 16 + r) * 32 + kg);
        #pragma unroll
        for (int n = 0; n < NFRAG; n++)
            bF[n] = *reinterpret_cast<const bf16x8*>(Bs[cb] + ((BN / 2) * wc + n * 16 + r) * 32 + kg);
        #pragma unroll
        for (int m = 0; m < 4; m++)
            #pragma unroll
            for (int n = 0; n < NFRAG; n++)
                acc[m][n] = __builtin_amdgcn_mfma_f32_16x16x32_bf16(aF[m], bF[n], acc[m][n], 0, 0, 0);

        MEM_FENCE();                    // keep LDS reads above the barrier
        __builtin_amdgcn_s_barrier();   // all waves done reading buf cb
        if (t + DEPTH < nt) stage(cb, (t + DEPTH) << 5);   // overwrite cb, fly ahead
        cb = (cb + 1 == DEPTH) ? 0 : cb + 1;
    }

    int row0 = brow + 64 * wr + ((lane >> 4) * 4);
    int col0 = bcol + (BN / 2) * wc + (lane & 15);
    #pragma unroll
    for (int m = 0; m < 4; m++) {
        #pragma unroll
        for (int n = 0; n < NFRAG; n++) {
            int ccol = col0 + n * 16;
            float bv = bias[ccol];
            #pragma unroll
            for (int q = 0; q < 4; q++) {
                int rrow = row0 + m * 16 + q;
                float o = acc[m][n][q] + bv;
                if (EPI == 0) {
                    Cb[(size_t)rrow * N + ccol] = __float2bfloat16(o);
                } else if (EPI == 1) {
                    o = o / (1.0f + __expf(-o));
                    Cb[(size_t)rrow * N + ccol] = __float2bfloat16(o);
                } else {
                    o += res[(size_t)rrow * N + ccol];
                    Cf[(size_t)rrow * N + ccol] = o;
                }
            }
        }
    }
}

// ---------------- RoPE + relayout: [M][rowStride] bf16 -> [B,H,S,64] bf16 ----------------
__global__ void rope_relayout(const __hip_bfloat16* __restrict__ Xn, int rowStride,
                              __hip_bfloat16* __restrict__ Xh, float scale) {
    int idx = blockIdx.x * 256 + threadIdx.x;    // M * 512 threads
    int pc = idx & 511;
    int row = idx >> 9;
    int d = pc * 2;
    int h = d >> 6, dh = d & 63;
    int s = row >> 2, b = row & 3;
    union { unsigned u; __hip_bfloat16 h2[2]; } cv;
    cv.u = *reinterpret_cast<const unsigned*>(Xn + (size_t)row * rowStride + d);
    float f0 = __bfloat162float(cv.h2[0]);
    float f1 = __bfloat162float(cv.h2[1]);
    if (dh < 32) {
        int p = dh >> 1;
        float ang = (float)s * __powf(10000.f, -(float)p * (1.0f / 16.0f));
        float c, sn;
        __sincosf(ang, &sn, &c);
        float r0 = f0 * c - f1 * sn;
        float r1 = f1 * c + f0 * sn;
        f0 = r0; f1 = r1;
    }
    cv.h2[0] = __float2bfloat16(f0 * scale);
    cv.h2[1] = __float2bfloat16(f1 * scale);
    *reinterpret_cast<unsigned*>(Xh + ((size_t)(b * HH + h) * SS + s) * 64 + dh) = cv.u;
}

// ---------------- V transpose: [M][rowStride] bf16 -> [B,H,64,S] bf16 ----------------
__global__ void vtrans_kernel(const __hip_bfloat16* __restrict__ Vn, int rowStride,
                              __hip_bfloat16* __restrict__ Vt) {
    __shared__ __hip_bfloat16 t[64][72];
    int tid = threadIdx.x;
    int bh = blockIdx.y, b = bh >> 4, h = bh & 15;
    int s0 = blockIdx.x * 64;
    #pragma unroll
    for (int i = 0; i < 2; i++) {
        int f = tid + i * 256;
        int sr = f >> 3, c = (f & 7) * 8;
        *reinterpret_cast<uint4*>(&t[sr][c]) =
            *reinterpret_cast<const uint4*>(Vn + (size_t)((s0 + sr) * BB + b) * rowStride + h * 64 + c);
    }
    __syncthreads();
    #pragma unroll
    for (int i = 0; i < 2; i++) {
        int f = tid + i * 256;
        int d = f >> 3, c = (f & 7) * 8;
        __hip_bfloat16 tmp[8];
        #pragma unroll
        for (int j = 0; j < 8; j++) tmp[j] = t[c + j][d];
        *reinterpret_cast<uint4*>(Vt + ((size_t)bh * 64 + d) * SS + s0 + c) =
            *reinterpret_cast<uint4*>(tmp);
    }
}

// ---------------- MFMA flash attention (unchanged, passing) ----------------
template<bool CAUSAL>
__global__ __launch_bounds__(256) void attn_mfma(
    const __hip_bfloat16* __restrict__ Qh, const __hip_bfloat16* __restrict__ Kh,
    const __hip_bfloat16* __restrict__ Vth, __hip_bfloat16* __restrict__ O)
{
    __shared__ __hip_bfloat16 Ks[2][64 * 64];
    __shared__ __hip_bfloat16 Vs[2][64 * 64];
    __shared__ __hip_bfloat16 Ps[4][16][72];
    int tid = threadIdx.x, lane = tid & 63, w = tid >> 6;
    int r = lane & 15, g = lane >> 4;
    int bh = blockIdx.y;
    int b = bh >> 4, h = bh & 15;
    int qb = blockIdx.x * 64;
    const __hip_bfloat16* gQ = Qh + (size_t)bh * SS * 64;
    const __hip_bfloat16* gK = Kh + (size_t)bh * SS * 64;
    const __hip_bfloat16* gV = Vth + (size_t)bh * 64 * SS;

    bf16x8 qf0 = *reinterpret_cast<const bf16x8*>(gQ + (size_t)(qb + w * 16 + r) * 64 + g * 8);
    bf16x8 qf1 = *reinterpret_cast<const bf16x8*>(gQ + (size_t)(qb + w * 16 + r) * 64 + 32 + g * 8);

    f32x4 accO[4];
    float mreg[4], lreg[4];
    #pragma unroll
    for (int j = 0; j < 4; j++) {
        accO[j] = (f32x4){0.f, 0.f, 0.f, 0.f};
        mreg[j] = -1e38f; lreg[j] = 0.f;
    }

    int nt = CAUSAL ? (blockIdx.x + 1) : (SS / 64);

    auto stage = [&](int buf, int kt) {
        #pragma unroll
        for (int i = 0; i < 2; i++) {
            int f = i * 256 + tid;
            int row = f >> 3, cp = f & 7;
            int cs = cp ^ (row & 7);
            __builtin_amdgcn_global_load_lds(
                (const __attribute__((address_space(1))) void*)(gK + (size_t)(kt + row) * 64 + cs * 8),
                (__attribute__((address_space(3))) void*)(&Ks[buf][(i * 256 + w * 64) * 8]),
                16, 0, 0);
            __builtin_amdgcn_global_load_lds(
                (const __attribute__((address_space(1))) void*)(gV + (size_t)row * SS + kt + cs * 8),
                (__attribute__((address_space(3))) void*)(&Vs[buf][(i * 256 + w * 64) * 8]),
                16, 0, 0);
        }
    };

    stage(0, 0);
    __syncthreads();
    int cur = 0;
    for (int t = 0; t < nt; t++) {
        if (t + 1 < nt) stage(cur ^ 1, (t + 1) * 64);
        int kt = t * 64;

        f32x4 sa[4];
        #pragma unroll
        for (int ks = 0; ks < 4; ks++) {
            sa[ks] = (f32x4){0.f, 0.f, 0.f, 0.f};
            int rk = ks * 16 + r;
            bf16x8 kf0 = *reinterpret_cast<const bf16x8*>(&Ks[cur][rk * 64 + ((g ^ (rk & 7)) * 8)]);
            bf16x8 kf1 = *reinterpret_cast<const bf16x8*>(&Ks[cur][rk * 64 + (((4 + g) ^ (rk & 7)) * 8)]);
            sa[ks] = __builtin_amdgcn_mfma_f32_16x16x32_bf16(qf0, kf0, sa[ks], 0, 0, 0);
            sa[ks] = __builtin_amdgcn_mfma_f32_16x16x32_bf16(qf1, kf1, sa[ks], 0, 0, 0);
        }

        if (CAUSAL && t == nt - 1) {
            #pragma unroll
            for (int ks = 0; ks < 4; ks++) {
                int key = kt + ks * 16 + r;
                #pragma unroll
                for (int j = 0; j < 4; j++) {
                    int qq = qb + w * 16 + g * 4 + j;
                    if (key > qq) sa[ks][j] = -1e9f;
                }
            }
        }

        #pragma unroll
        for (int j = 0; j < 4; j++) {
            float mx = fmaxf(fmaxf(sa[0][j], sa[1][j]), fmaxf(sa[2][j], sa[3][j]));
            mx = fmaxf(mx, __shfl_xor(mx, 1));
            mx = fmaxf(mx, __shfl_xor(mx, 2));
            mx = fmaxf(mx, __shfl_xor(mx, 4));
            mx = fmaxf(mx, __shfl_xor(mx, 8));
            float nm = fmaxf(mreg[j], mx);
            float alpha = __expf(mreg[j] - nm);
            mreg[j] = nm;
            float ps = 0.f;
            #pragma unroll
            for (int ks = 0; ks < 4; ks++) {
                float p = __expf(sa[ks][j] - nm);
                sa[ks][j] = p;
                ps += p;
            }
            ps += __shfl_xor(ps, 1);
            ps += __shfl_xor(ps, 2);
            ps += __shfl_xor(ps, 4);
            ps += __shfl_xor(ps, 8);
            lreg[j] = lreg[j] * alpha + ps;
            #pragma unroll
            for (int ds = 0; ds < 4; ds++) accO[ds][j] *= alpha;
        }

        #pragma unroll
        for (int ks = 0; ks < 4; ks++)
            #pragma unroll
            for (int j = 0; j < 4; j++)
                Ps[w][g * 4 + j][ks * 16 + r] = __float2bfloat16(sa[ks][j]);

        #pragma unroll
        for (int ks2 = 0; ks2 < 2; ks2++) {
            bf16x8 pf = *reinterpret_cast<const bf16x8*>(&Ps[w][r][ks2 * 32 + g * 8]);
            #pragma unroll
            for (int ds = 0; ds < 4; ds++) {
                int rv = ds * 16 + r;
                bf16x8 vf = *reinterpret_cast<const bf16x8*>(
                    &Vs[cur][rv * 64 + (((ks2 * 4 + g) ^ (rv & 7)) * 8)]);
                accO[ds] = __builtin_amdgcn_mfma_f32_16x16x32_bf16(pf, vf, accO[ds], 0, 0, 0);
            }
        }
        cur ^= 1;
        __syncthreads();
    }

    #pragma unroll
    for (int j = 0; j < 4; j++) {
        float inv = 1.0f / lreg[j];
        int s = qb + w * 16 + g * 4 + j;
        #pragma unroll
        for (int ds = 0; ds < 4; ds++)
            O[(size_t)(s * BB + b) * DD + h * 64 + ds * 16 + r] =
                __float2bfloat16(accO[ds][j] * inv);
    }
}

extern "C" void kernel_launch(void* const* d_in, const int* in_sizes, int n_in,
                              void* d_out, int out_size, void* d_ws, size_t ws_size,
                              hipStream_t stream) {
    const float* x    = (const float*)d_in[0];
    const float* enc  = (const float*)d_in[1];
    const float* sa_wq = (const float*)d_in[3];
    const float* sa_bq = (const float*)d_in[4];
    const float* sa_wk = (const float*)d_in[5];
    const float* sa_bk = (const float*)d_in[6];
    const float* sa_wv = (const float*)d_in[7];
    const float* sa_bv = (const float*)d_in[8];
    const float* sa_wo = (const float*)d_in[9];
    const float* sa_bo = (const float*)d_in[10];
    const float* ca_wq = (const float*)d_in[11];
    const float* ca_bq = (const float*)d_in[12];
    const float* ca_wk = (const float*)d_in[13];
    const float* ca_bk = (const float*)d_in[14];
    const float* ca_wv = (const float*)d_in[15];
    const float* ca_bv = (const float*)d_in[16];
    const float* ca_wo = (const float*)d_in[17];
    const float* ca_bo = (const float*)d_in[18];
    const float* ff_w1 = (const float*)d_in[19];
    const float* ff_b1 = (const float*)d_in[20];
    const float* ff_w2 = (const float*)d_in[21];
    const float* ff_b2 = (const float*)d_in[22];
    const float* g1 = (const float*)d_in[23];
    const float* g2 = (const float*)d_in[24];
    const float* g3 = (const float*)d_in[25];
    float* out = (float*)d_out;

    // ---- workspace map (112 MB) ----
    const size_t MB = 1024 * 1024;
    char* base = (char*)d_ws;
    __hip_bfloat16* sa_qkvT = (__hip_bfloat16*)(base + 0 * MB);   // [3072][1024] 6MB
    __hip_bfloat16* sa_woT  = (__hip_bfloat16*)(base + 6 * MB);   // 2MB
    __hip_bfloat16* ca_wqT  = (__hip_bfloat16*)(base + 8 * MB);   // 2MB
    __hip_bfloat16* ca_kvT  = (__hip_bfloat16*)(base + 10 * MB);  // [2048][1024] 4MB
    __hip_bfloat16* ca_woT  = (__hip_bfloat16*)(base + 14 * MB);  // 2MB
    __hip_bfloat16* w1T     = (__hip_bfloat16*)(base + 16 * MB);  // [FFF][DD] 8MB
    __hip_bfloat16* w2T     = (__hip_bfloat16*)(base + 24 * MB);  // [DD][FFF] 8MB
    float* sa_bqkv = (float*)(base + 32 * MB);                    // 3072 f
    float* ca_bkv  = (float*)(base + 32 * MB + 16384);            // 2048 f
    __hip_bfloat16* xnb   = (__hip_bfloat16*)(base + 33 * MB);    // 8MB (also attnb)
    __hip_bfloat16* qkv   = (__hip_bfloat16*)(base + 41 * MB);    // [M][3072] 24MB
    __hip_bfloat16* Qhp   = (__hip_bfloat16*)(base + 65 * MB);    // 8MB (also encb)
    __hip_bfloat16* Khp   = (__hip_bfloat16*)(base + 73 * MB);    // 8MB
    __hip_bfloat16* Vtp   = (__hip_bfloat16*)(base + 81 * MB);    // 8MB
    float* x1 = (float*)(base + 96 * MB);                         // 16MB -> 112
    __hip_bfloat16* attnb = xnb;
    __hip_bfloat16* encb  = Qhp;
    __hip_bfloat16* qn    = qkv;                                  // CA: [M][1024] 8MB
    __hip_bfloat16* kvb   = qkv + (size_t)4 * MB;                 // CA: [M][2048] 16MB
    __hip_bfloat16* hb    = qkv;                                  // FFN: [M][FFF] 32MB (41..73)

    dim3 blk(256);
    dim3 gT8(32, 32, 8);
    dim3 gW1(FFF / 32, DD / 32);
    dim3 gW2(DD / 32, FFF / 32);
    dim3 gQKV(3072 / 128, MM / 128);   // 24 x 32 = 768
    dim3 gKV(2048 / 128, MM / 128);    // 16 x 32 = 512
    dim3 gN64(DD / 64, MM / 128);      // 16 x 32 = 512
    dim3 gF1(FFF / 128, MM / 128);     // 32 x 32 = 1024
    dim3 gAtt(SS / 64, BB * HH);
    int ropeBlocks = MM * 512 / 256;

    // ---- one-time conversions ----
    wtrans8_kernel<<<gT8, blk, 0, stream>>>(
        sa_wq, sa_wk, sa_wv, sa_wo, ca_wq, ca_wk, ca_wv, ca_wo,
        sa_qkvT, sa_qkvT + (size_t)1024 * DD, sa_qkvT + (size_t)2048 * DD, sa_woT,
        ca_wqT, ca_kvT, ca_kvT + (size_t)1024 * DD, ca_woT);
    wtrans_kernel<<<gW1, blk, 0, stream>>>(ff_w1, w1T, DD, FFF);
    wtrans_kernel<<<gW2, blk, 0, stream>>>(ff_w2, w2T, FFF, DD);
    bias_concat<<<12, blk, 0, stream>>>(sa_bq, sa_bk, sa_bv, sa_bqkv, DD);
    bias_concat<<<8, blk, 0, stream>>>(ca_bk, ca_bv, nullptr, ca_bkv, DD);

    // ---- self-attention block ----
    rmsnorm_kernel<<<MM, blk, 0, stream>>>(x, g1, xnb);
    gemm_bf16<0, 128><<<gQKV, blk, 0, stream>>>(xnb, sa_qkvT, sa_bqkv, nullptr, nullptr, qkv, DD, 3072);
    rope_relayout<<<ropeBlocks, blk, 0, stream>>>(qkv, 3072, Qhp, 0.125f);
    rope_relayout<<<ropeBlocks, blk, 0, stream>>>(qkv + 1024, 3072, Khp, 1.0f);
    vtrans_kernel<<<gAtt, blk, 0, stream>>>(qkv + 2048, 3072, Vtp);
    attn_mfma<true><<<gAtt, blk, 0, stream>>>(Qhp, Khp, Vtp, attnb);
    gemm_bf16<2, 64><<<gN64, blk, 0, stream>>>(attnb, sa_woT, sa_bo, x, x1, nullptr, DD, DD);

    // ---- cross-attention block ----
    rmsnorm_kernel<<<MM, blk, 0, stream>>>(x1, g2, xnb);
    f2b_kernel<<<(MM * DD / 4) / 256, blk, 0, stream>>>(enc, encb);
    gemm_bf16<0, 128><<<gKV, blk, 0, stream>>>(encb, ca_kvT, ca_bkv, nullptr, nullptr, kvb, DD, 2048);
    gemm_bf16<0, 64><<<gN64, blk, 0, stream>>>(xnb, ca_wqT, ca_bq, nullptr, nullptr, qn, DD, DD);
    rope_relayout<<<ropeBlocks, blk, 0, stream>>>(qn, 1024, Qhp, 0.125f);
    rope_relayout<<<ropeBlocks, blk, 0, stream>>>(kvb, 2048, Khp, 1.0f);
    vtrans_kernel<<<gAtt, blk, 0, stream>>>(kvb + 1024, 2048, Vtp);
    attn_mfma<false><<<gAtt, blk, 0, stream>>>(Qhp, Khp, Vtp, attnb);
    gemm_bf16<2, 64><<<gN64, blk, 0, stream>>>(attnb, ca_woT, ca_bo, x1, x1, nullptr, DD, DD);

    // ---- FFN block ----
    rmsnorm_kernel<<<MM, blk, 0, stream>>>(x1, g3, xnb);
    gemm_bf16<1, 128><<<gF1, blk, 0, stream>>>(xnb, w1T, ff_b1, nullptr, nullptr, hb, DD, FFF);
    gemm_bf16<2, 64><<<gN64, blk, 0, stream>>>(hb, w2T, ff_b2, x1, out, nullptr, FFF, DD);
}